// Round 5
// baseline (433.831 us; speedup 1.0000x reference)
//
#include <hip/hip_runtime.h>
#include <hip/hip_bf16.h>
#include <math.h>

#define NN 50000
#define NE 800000
#define HB 782      // hist/scatter blocks (1024 edges each)
#define GB64 782    // cdiv(N,64) — M=64 gemm blocks
#define GB128 1563  // cdiv(N,32) — M=128 gemm blocks
#define WCB 16
#define ZSB 1563    // zscale blocks (8 halves/thread)
#define SPB 12500   // cdiv(N,4) — spmm blocks (4 rows/block, 1 wave/row)

typedef _Float16 half4v __attribute__((ext_vector_type(4)));

static inline int cdiv(int a, int b) { return (a + b - 1) / b; }

// ---------------- small helpers ----------------

__global__ void k_zero_i(int* __restrict__ p, int n) {
    int i = blockIdx.x * blockDim.x + threadIdx.x;
    if (i < n) p[i] = 0;
}

__device__ void hist_dev(int bx, const int* __restrict__ src, const int* __restrict__ dst,
                         int* __restrict__ degin, int* __restrict__ degout, int E) {
    int idx = bx * 256 + threadIdx.x;
    int nthr = HB * 256;
#pragma unroll
    for (int j = 0; j < 4; j++) {
        int e = idx + j * nthr;
        if (e < E) {
            atomicAdd(&degin[dst[e]], 1);
            atomicAdd(&degout[src[e]], 1);
        }
    }
}

__device__ void scatter_dev(int bx, const int* __restrict__ src, const int* __restrict__ dst,
                            int* __restrict__ cursor, int* __restrict__ cols, int E) {
    int idx = bx * 256 + threadIdx.x;
    int nthr = HB * 256;
#pragma unroll
    for (int j = 0; j < 4; j++) {
        int e = idx + j * nthr;
        if (e < E) {
            int p = atomicAdd(&cursor[dst[e]], 1);
            cols[p] = src[e];
        }
    }
}

__device__ void wc_dev(int bx, const float* __restrict__ W3, float* __restrict__ wc) {
    int i = bx * 256 + threadIdx.x;
    if (i >= 4096) return;
    int r = i >> 6, c = i & 63;
    float w0 = W3[(0 * 64 + r) * 64 + c];
    float w1 = W3[(1 * 64 + r) * 64 + c];
    float w2 = W3[(2 * 64 + r) * 64 + c];
    float w3 = W3[(3 * 64 + r) * 64 + c];
    float w4 = W3[(4 * 64 + r) * 64 + c];
    wc[i]        = 3.f * w0;
    wc[4096 + i] = -3.f * w0 + 3.f * w1 + w3;
    wc[8192 + i] = 0.75f * w0 - 1.5f * w1 + 0.75f * w2 + w4;
}

__device__ void zscale_dev(int bx, half4v* __restrict__ zh, const float* __restrict__ dout, int N) {
    int idx = bx * 256 + threadIdx.x;   // 8 halves per thread
    if (idx >= N * 8) return;
    int row = idx >> 3;
    float m = dout[row];
    half4v a = zh[idx * 2], b = zh[idx * 2 + 1];
    a.x = (_Float16)((float)a.x * m); a.y = (_Float16)((float)a.y * m);
    a.z = (_Float16)((float)a.z * m); a.w = (_Float16)((float)a.w * m);
    b.x = (_Float16)((float)b.x * m); b.y = (_Float16)((float)b.y * m);
    b.z = (_Float16)((float)b.z * m); b.w = (_Float16)((float)b.w * m);
    zh[idx * 2] = a; zh[idx * 2 + 1] = b;
}

// ---- parallel exclusive scan ----

__global__ void k_scanA(const int* __restrict__ deg, int* __restrict__ cursor,
                        int* __restrict__ bsum, int N) {
    __shared__ int sh[256];
    int t = threadIdx.x;
    int i = blockIdx.x * 256 + t;
    int v = (i < N) ? deg[i] : 0;
    sh[t] = v;
    __syncthreads();
    for (int off = 1; off < 256; off <<= 1) {
        int y = (t >= off) ? sh[t - off] : 0;
        __syncthreads();
        sh[t] += y;
        __syncthreads();
    }
    if (i < N) cursor[i] = sh[t] - v;
    if (t == 255) bsum[blockIdx.x] = sh[255];
}

__global__ void k_scanB(int* __restrict__ bsum, int* __restrict__ boff, int nb) {
    __shared__ int sh[256];
    int t = threadIdx.x;
    int v = (t < nb) ? bsum[t] : 0;
    sh[t] = v;
    __syncthreads();
    for (int off = 1; off < 256; off <<= 1) {
        int y = (t >= off) ? sh[t - off] : 0;
        __syncthreads();
        sh[t] += y;
        __syncthreads();
    }
    if (t < nb) boff[t] = sh[t] - v;
}

__global__ void k_scanC_inv(int* __restrict__ cursor, const int* __restrict__ boff,
                            const int* __restrict__ degin, const int* __restrict__ degout,
                            float* __restrict__ din, float* __restrict__ dout, int N) {
    int i = blockIdx.x * blockDim.x + threadIdx.x;
    if (i < N) {
        cursor[i] += boff[blockIdx.x];
        int a = degin[i]; if (a < 1) a = 1;
        int b = degout[i]; if (b < 1) b = 1;
        din[i] = rsqrtf((float)a);
        dout[i] = rsqrtf((float)b);
    }
}

// ---------------- register-tiled GEMM device function ----------------
// C[N,M] = relu?( A[N,K] @ W[K,M] + bias ); optional fp16 mirror Ch = half(C*mscale);
// optional OUTW head: out[row,0:2] = (post-relu row) @ W4 + b4 via cross-lane reduce.

struct ASeg { const void* p; int ld; };
struct AArgs { ASeg s[3]; };

template <int M, bool RELU, bool OUTW, bool AHALF>
__device__ void gemm_dev(float* smem, int bx, AArgs A, int K,
                         const float* __restrict__ W, const float* __restrict__ bias,
                         float* __restrict__ C, half4v* __restrict__ Ch,
                         const float* __restrict__ mscale,
                         const float* __restrict__ W4, const float* __restrict__ b4,
                         float* __restrict__ outp, int N) {
    constexpr int TX = M / 4;
    constexpr int TYN = 256 / TX;
    constexpr int BM = TYN * 4;
    constexpr int AP = BM + 4;
    float* At = smem;
    float* Ws = smem + 64 * AP;
    int tid = threadIdx.x;
    int tx = tid % TX, ty = tid / TX;
    int row0 = bx * BM;
    float acc[4][4] = {{0.f}};
    int nt = K / 64;
    for (int t = 0; t < nt; t++) {
        {
            int k16 = tid % 16;
            int kk = k16 * 4;
            for (int r = tid / 16; r < BM; r += 16) {
                int row = row0 + r;
                float4 v = {0.f, 0.f, 0.f, 0.f};
                if (row < N) {
                    if (AHALF) {
                        const half4v* Ap = (const half4v*)A.s[t].p;
                        half4v hv = Ap[(size_t)row * (A.s[t].ld / 4) + k16];
                        v.x = (float)hv.x; v.y = (float)hv.y;
                        v.z = (float)hv.z; v.w = (float)hv.w;
                    } else {
                        const float* Ap = (const float*)A.s[t].p;
                        v = *(const float4*)(Ap + (size_t)row * A.s[t].ld + kk);
                    }
                }
                At[(kk + 0) * AP + r] = v.x;
                At[(kk + 1) * AP + r] = v.y;
                At[(kk + 2) * AP + r] = v.z;
                At[(kk + 3) * AP + r] = v.w;
            }
        }
        {
            const float* Wt = W + t * 64 * M;
            for (int i = tid * 4; i < 64 * M; i += 1024)
                *(float4*)(Ws + i) = *(const float4*)(Wt + i);
        }
        __syncthreads();
#pragma unroll 16
        for (int k = 0; k < 64; k++) {
            float4 a = *(const float4*)(At + k * AP + ty * 4);
            float4 w = *(const float4*)(Ws + k * M + tx * 4);
            acc[0][0] += a.x * w.x; acc[0][1] += a.x * w.y; acc[0][2] += a.x * w.z; acc[0][3] += a.x * w.w;
            acc[1][0] += a.y * w.x; acc[1][1] += a.y * w.y; acc[1][2] += a.y * w.z; acc[1][3] += a.y * w.w;
            acc[2][0] += a.z * w.x; acc[2][1] += a.z * w.y; acc[2][2] += a.z * w.z; acc[2][3] += a.z * w.w;
            acc[3][0] += a.w * w.x; acc[3][1] += a.w * w.y; acc[3][2] += a.w * w.z; acc[3][3] += a.w * w.w;
        }
        __syncthreads();
    }
    float4 b = {0.f, 0.f, 0.f, 0.f};
    if (bias) b = *(const float4*)(bias + tx * 4);
    float w40[4], w41[4];
    if (OUTW) {
#pragma unroll
        for (int cc = 0; cc < 4; cc++) {
            w40[cc] = W4[(tx * 4 + cc) * 2];
            w41[cc] = W4[(tx * 4 + cc) * 2 + 1];
        }
    }
#pragma unroll
    for (int i = 0; i < 4; i++) {
        int row = row0 + ty * 4 + i;
        float4 o;
        o.x = acc[i][0] + b.x; o.y = acc[i][1] + b.y;
        o.z = acc[i][2] + b.z; o.w = acc[i][3] + b.w;
        if (RELU) {
            o.x = fmaxf(o.x, 0.f); o.y = fmaxf(o.y, 0.f);
            o.z = fmaxf(o.z, 0.f); o.w = fmaxf(o.w, 0.f);
        }
        if (OUTW) {
            float p0 = o.x * w40[0] + o.y * w40[1] + o.z * w40[2] + o.w * w40[3];
            float p1 = o.x * w41[0] + o.y * w41[1] + o.z * w41[2] + o.w * w41[3];
#pragma unroll
            for (int off = 1; off < 16; off <<= 1) {
                p0 += __shfl_xor(p0, off);
                p1 += __shfl_xor(p1, off);
            }
            if (tx == 0 && row < N) {
                outp[(size_t)row * 2 + 0] = p0 + b4[0];
                outp[(size_t)row * 2 + 1] = p1 + b4[1];
            }
        }
        if (row < N) {
            if (C) *(float4*)(C + (size_t)row * M + tx * 4) = o;
            if (Ch) {
                float m = mscale ? mscale[row] : 1.f;
                half4v hv;
                hv.x = (_Float16)(o.x * m); hv.y = (_Float16)(o.y * m);
                hv.z = (_Float16)(o.z * m); hv.w = (_Float16)(o.w * m);
                Ch[((size_t)row * M) / 4 + tx] = hv;
            }
        }
    }
}

// ---------------- fused kernels ----------------

// F1: hist || wc || a1 (in_feat@W1 -> h1 fp16 mirror) || a5 (in_feat@Wg1 -> Z fp16)
__launch_bounds__(256)
__global__ void k_F1(const float* __restrict__ in_feat, const float* __restrict__ W1,
                     const float* __restrict__ b1, const float* __restrict__ Wg1,
                     const float* __restrict__ W3, float* __restrict__ wc,
                     half4v* __restrict__ h1h, half4v* __restrict__ zh,
                     const int* __restrict__ src, const int* __restrict__ dst,
                     int* __restrict__ degin, int* __restrict__ degout, int E, int N) {
    __shared__ float smem[8448];
    int bx = blockIdx.x;
    if (bx < HB) { hist_dev(bx, src, dst, degin, degout, E); return; }
    bx -= HB;
    if (bx < WCB) { wc_dev(bx, W3, wc); return; }
    bx -= WCB;
    AArgs A;
    A.s[0] = {in_feat, 128}; A.s[1] = {in_feat + 64, 128}; A.s[2] = {nullptr, 0};
    if (bx < GB64) {
        gemm_dev<64, true, false, false>(smem, bx, A, 128, W1, b1,
            nullptr, h1h, nullptr, nullptr, nullptr, nullptr, N);
        return;
    }
    bx -= GB64;
    gemm_dev<64, false, false, false>(smem, bx, A, 128, Wg1, nullptr,
        nullptr, zh, nullptr, nullptr, nullptr, nullptr, N);
}

// F2: scatter || a2 (h1h@W2 -> h f32 + h*din fp16 mirror, in-place) || zscale (zh *= dout)
__launch_bounds__(256)
__global__ void k_F2(half4v* __restrict__ h1h, const float* __restrict__ W2,
                     const float* __restrict__ b2, float* __restrict__ bufh,
                     const float* __restrict__ din, const float* __restrict__ dout,
                     half4v* __restrict__ zh,
                     const int* __restrict__ src, const int* __restrict__ dst,
                     int* __restrict__ cursor, int* __restrict__ cols, int E, int N) {
    __shared__ float smem[8448];
    int bx = blockIdx.x;
    if (bx < HB) { scatter_dev(bx, src, dst, cursor, cols, E); return; }
    bx -= HB;
    if (bx < GB64) {
        AArgs A;
        A.s[0] = {h1h, 64}; A.s[1] = {nullptr, 0}; A.s[2] = {nullptr, 0};
        gemm_dev<64, true, false, true>(smem, bx, A, 64, W2, b2,
            bufh, h1h, din, nullptr, nullptr, nullptr, N);
        return;
    }
    bx -= GB64;
    zscale_dev(bx, zh, dout, N);
}

// ---------------- edge-parallel pull SpMM: 1 wave per row ----------------

struct SpmmP {
    const half4v* xh; const float* fsub; const float* rowscale; const float* bias;
    float* y; half4v* yh; const float* mscale; int relu;
};

__launch_bounds__(256)
__global__ void k_fs(SpmmP P0, SpmmP P1, const int* __restrict__ cols,
                     const int* __restrict__ cursor, const int* __restrict__ deg, int N) {
    int bx = blockIdx.x;
    bool first = bx < SPB;
    const SpmmP& P = first ? P0 : P1;
    int row = (first ? bx : bx - SPB) * 4 + (threadIdx.x >> 6);
    if (row >= N) return;
    int lane = threadIdx.x & 63;
    int sub = lane >> 4, c = lane & 15;
    int end = cursor[row];
    int start = end - deg[row];
    float ax = 0.f, ay = 0.f, az = 0.f, aw = 0.f;
    for (int e = start + sub; e < end; e += 4) {
        int s = cols[e];
        half4v v = P.xh[(size_t)s * 16 + c];
        ax += (float)v.x; ay += (float)v.y; az += (float)v.z; aw += (float)v.w;
    }
    ax += __shfl_xor(ax, 16); ay += __shfl_xor(ay, 16);
    az += __shfl_xor(az, 16); aw += __shfl_xor(aw, 16);
    ax += __shfl_xor(ax, 32); ay += __shfl_xor(ay, 32);
    az += __shfl_xor(az, 32); aw += __shfl_xor(aw, 32);
    if (sub != 0) return;
    size_t oidx = (size_t)row * 16 + c;
    if (P.fsub) {
        float m = P.rowscale[row];
        float4 f = ((const float4*)P.fsub)[oidx];
        ax = f.x - ax * m; ay = f.y - ay * m;
        az = f.z - az * m; aw = f.w - aw * m;
    } else {
        if (P.rowscale) { float m = P.rowscale[row]; ax *= m; ay *= m; az *= m; aw *= m; }
        if (P.bias) {
            float4 bb = ((const float4*)P.bias)[c];
            ax += bb.x; ay += bb.y; az += bb.z; aw += bb.w;
        }
        if (P.relu) {
            ax = fmaxf(ax, 0.f); ay = fmaxf(ay, 0.f);
            az = fmaxf(az, 0.f); aw = fmaxf(aw, 0.f);
        }
    }
    if (P.y) { float4 o = {ax, ay, az, aw}; ((float4*)P.y)[oidx] = o; }
    if (P.yh) {
        float m = P.mscale ? P.mscale[row] : 1.f;
        half4v hv;
        hv.x = (_Float16)(ax * m); hv.y = (_Float16)(ay * m);
        hv.z = (_Float16)(az * m); hv.w = (_Float16)(aw * m);
        P.yh[oidx] = hv;
    }
}

// F3: a3 ([h|L1|L2]@Wc + b3 -> relu -> @W4+b4 -> out) || a6 (SGh@Wg2+bg2 -> emb)
__launch_bounds__(256)
__global__ void k_F3(const float* __restrict__ bufh, const float* __restrict__ bufl1,
                     const float* __restrict__ bufl2, const float* __restrict__ wc,
                     const float* __restrict__ b3, const float* __restrict__ W4,
                     const float* __restrict__ b4, float* __restrict__ outp,
                     const half4v* __restrict__ sgh, const float* __restrict__ Wg2,
                     const float* __restrict__ bg2, float* __restrict__ emb, int N) {
    __shared__ float smem[10496];
    int bx = blockIdx.x;
    if (bx < GB64) {
        AArgs A;
        A.s[0] = {bufh, 64}; A.s[1] = {bufl1, 64}; A.s[2] = {bufl2, 64};
        gemm_dev<64, true, true, false>(smem, bx, A, 192, wc, b3,
            nullptr, nullptr, nullptr, W4, b4, outp, N);
        return;
    }
    bx -= GB64;
    AArgs A;
    A.s[0] = {sgh, 64}; A.s[1] = {nullptr, 0}; A.s[2] = {nullptr, 0};
    gemm_dev<128, false, false, true>(smem, bx, A, 64, Wg2, bg2,
        emb, nullptr, nullptr, nullptr, nullptr, nullptr, N);
}

extern "C" void kernel_launch(void* const* d_in, const int* in_sizes, int n_in,
                              void* d_out, int out_size, void* d_ws, size_t ws_size,
                              hipStream_t stream) {
    const int N = NN, E = NE;
    const float* in_feat = (const float*)d_in[0];
    const int* src = (const int*)d_in[1];
    const int* dst = (const int*)d_in[2];
    const float* W1 = (const float*)d_in[3];
    const float* b1 = (const float*)d_in[4];
    const float* W2 = (const float*)d_in[5];
    const float* b2 = (const float*)d_in[6];
    const float* W3 = (const float*)d_in[7];
    const float* b3 = (const float*)d_in[8];
    const float* W4 = (const float*)d_in[9];
    const float* b4 = (const float*)d_in[10];
    const float* Wg1 = (const float*)d_in[11];
    const float* bg1 = (const float*)d_in[12];
    const float* Wg2 = (const float*)d_in[13];
    const float* bg2 = (const float*)d_in[14];

    float* out = (float*)d_out;                 // [N,2]
    float* emb = out + (size_t)N * 2;           // [N,128]

    // workspace layout
    float* fw = (float*)d_ws;
    float* din  = fw;                      // [N]
    float* dout = din + N;                 // [N]
    float* buf1 = dout + N;                // [N,64] h (f32)
    float* buf2 = buf1 + (size_t)64 * N;   // [N,64] L1 (f32)
    float* buf3 = buf2 + (size_t)64 * N;   // [N,64] L2 (f32)
    float* wc   = buf3 + (size_t)64 * N;   // [3,64,64]
    half4v* hbuf0 = (half4v*)(wc + 3 * 4096);                      // h1 -> h*din -> SG*din
    half4v* hbuf1 = (half4v*)((_Float16*)hbuf0 + (size_t)64 * N);  // L1*din
    half4v* hbuf2 = (half4v*)((_Float16*)hbuf1 + (size_t)64 * N);  // Z -> Z*dout
    half4v* hbuf3 = (half4v*)((_Float16*)hbuf2 + (size_t)64 * N);  // g1*dout
    int* degin  = (int*)((_Float16*)hbuf3 + (size_t)64 * N);       // [N]
    int* degout = degin + N;               // [N]
    int* cursor = degout + N;              // [N]
    int* cols   = cursor + N;              // [E]
    int* bsum   = cols + E;                // [nb]
    int* boff   = bsum + 256;              // [nb]

    int nb = cdiv(N, 256);   // 196

    // 1) zero degree arrays
    k_zero_i<<<cdiv(2 * N, 256), 256, 0, stream>>>(degin, 2 * N);

    // 2) F1: hist || wc || a1 || a5
    k_F1<<<HB + WCB + 2 * GB64, 256, 0, stream>>>(in_feat, W1, b1, Wg1, W3, wc,
        hbuf0, hbuf2, src, dst, degin, degout, E, N);

    // 3-5) scan + degree norms
    k_scanA<<<nb, 256, 0, stream>>>(degin, cursor, bsum, N);
    k_scanB<<<1, 256, 0, stream>>>(bsum, boff, nb);
    k_scanC_inv<<<nb, 256, 0, stream>>>(cursor, boff, degin, degout, din, dout, N);

    // 6) F2: scatter || a2 || zscale
    k_F2<<<HB + GB64 + ZSB, 256, 0, stream>>>(hbuf0, W2, b2, buf1, din, dout, hbuf2,
        src, dst, cursor, cols, E, N);

    // 7) FS1: L1 = lap(h) [mirror L1*din] || g1 = relu(spmm(Z*dout)*din+bg1) [mirror g1*dout]
    SpmmP p0, p1;
    p0 = {hbuf0, buf1, din, nullptr, buf2, hbuf1, din, 0};
    p1 = {hbuf2, nullptr, din, bg1, nullptr, hbuf3, dout, 1};
    k_fs<<<2 * SPB, 256, 0, stream>>>(p0, p1, cols, cursor, degin, N);

    // 8) FS2: L2 = lap(L1) || SG = spmm(g1*dout) [mirror SG*din]
    p0 = {hbuf1, buf2, din, nullptr, buf3, nullptr, nullptr, 0};
    p1 = {hbuf3, nullptr, nullptr, nullptr, nullptr, hbuf0, din, 0};
    k_fs<<<2 * SPB, 256, 0, stream>>>(p0, p1, cols, cursor, degin, N);

    // 9) F3: out = relu([h|L1|L2]@Wc+b3)@W4+b4 || emb = SGh@Wg2+bg2
    k_F3<<<GB64 + GB128, 256, 0, stream>>>(buf1, buf2, buf3, wc, b3, W4, b4, out,
        hbuf0, Wg2, bg2, emb, N);
}

// Round 6
// 373.888 us; speedup vs baseline: 1.1603x; 1.1603x over previous
//
#include <hip/hip_runtime.h>
#include <hip/hip_bf16.h>
#include <math.h>

#define NN 50000
#define NE 800000
#define HB 782      // hist/scatter blocks (1024 edges each)
#define GB 782      // cdiv(N,64) — MFMA gemm blocks (64 rows/block)
#define CVB 3125    // cvt blocks (8 f32/thread)
#define SPB 12500   // cdiv(N,4) — spmm blocks (4 rows/block, 1 wave/row)

typedef _Float16 half8 __attribute__((ext_vector_type(8)));
typedef _Float16 half4v __attribute__((ext_vector_type(4)));
typedef float f32x4 __attribute__((ext_vector_type(4)));

static inline int cdiv(int a, int b) { return (a + b - 1) / b; }

// ---------------- small helpers ----------------

__global__ void k_zero_i(int* __restrict__ p, int n) {
    int i = blockIdx.x * blockDim.x + threadIdx.x;
    if (i < n) p[i] = 0;
}

__device__ void hist_dev(int bx, const int* __restrict__ src, const int* __restrict__ dst,
                         int* __restrict__ degin, int* __restrict__ degout, int E) {
    int idx = bx * 256 + threadIdx.x;
    int nthr = HB * 256;
#pragma unroll
    for (int j = 0; j < 4; j++) {
        int e = idx + j * nthr;
        if (e < E) {
            atomicAdd(&degin[dst[e]], 1);
            atomicAdd(&degout[src[e]], 1);
        }
    }
}

__device__ void scatter_dev(int bx, const int* __restrict__ src, const int* __restrict__ dst,
                            int* __restrict__ cursor, int* __restrict__ cols, int E) {
    int idx = bx * 256 + threadIdx.x;
    int nthr = HB * 256;
#pragma unroll
    for (int j = 0; j < 4; j++) {
        int e = idx + j * nthr;
        if (e < E) {
            int p = atomicAdd(&cursor[dst[e]], 1);
            cols[p] = src[e];
        }
    }
}

// cvt in_feat (f32) -> ih (fp16), 8 elems/thread
__device__ void cvt_dev(int bx, const float* __restrict__ x, _Float16* __restrict__ xh, int n8) {
    int idx = bx * 256 + threadIdx.x;
    if (idx >= n8) return;
    const float4* p = (const float4*)(x + idx * 8);
    float4 a = p[0], b = p[1];
    half8 h;
    h[0] = (_Float16)a.x; h[1] = (_Float16)a.y; h[2] = (_Float16)a.z; h[3] = (_Float16)a.w;
    h[4] = (_Float16)b.x; h[5] = (_Float16)b.y; h[6] = (_Float16)b.z; h[7] = (_Float16)b.w;
    *(half8*)(xh + idx * 8) = h;
}

// B-frag pack position for MFMA 16x16x32: W[k][n] (K x M, row-major)
__device__ inline size_t pack_pos(int k, int n, int K, int M) {
    int tile = n >> 4;
    int kstep = k >> 5;
    int quad = (k >> 3) & 3;
    int j = k & 7;
    int lane = (quad << 4) | (n & 15);
    return ((size_t)(tile * (K >> 5) + kstep) * 64 + lane) * 8 + j;
}

__device__ void pack_std_dev(int bx, const float* __restrict__ W, _Float16* __restrict__ Wpk,
                             int K, int M) {
    int idx = bx * 256 + threadIdx.x;
    if (idx >= K * M) return;
    int k = idx / M, n = idx % M;
    Wpk[pack_pos(k, n, K, M)] = (_Float16)W[idx];
}

// combine W3 branch blocks into folded [192,64] weight, packed
__device__ void pack_wc_dev(int bx, const float* __restrict__ W3, _Float16* __restrict__ wcpk) {
    int idx = bx * 256 + threadIdx.x;
    if (idx >= 3 * 4096) return;
    int b = idx >> 12;
    int rem = idx & 4095;
    int k = rem >> 6, n = rem & 63;
    float w0 = W3[(0 * 64 + k) * 64 + n];
    float w1 = W3[(1 * 64 + k) * 64 + n];
    float w2 = W3[(2 * 64 + k) * 64 + n];
    float w3 = W3[(3 * 64 + k) * 64 + n];
    float w4 = W3[(4 * 64 + k) * 64 + n];
    float v;
    if (b == 0)      v = 3.f * w0;
    else if (b == 1) v = -3.f * w0 + 3.f * w1 + w3;
    else             v = 0.75f * w0 - 1.5f * w1 + 0.75f * w2 + w4;
    wcpk[pack_pos(b * 64 + k, n, 192, 64)] = (_Float16)v;
}

// ---- parallel exclusive scan ----

__global__ void k_scanA(const int* __restrict__ deg, int* __restrict__ cursor,
                        int* __restrict__ bsum, int N) {
    __shared__ int sh[256];
    int t = threadIdx.x;
    int i = blockIdx.x * 256 + t;
    int v = (i < N) ? deg[i] : 0;
    sh[t] = v;
    __syncthreads();
    for (int off = 1; off < 256; off <<= 1) {
        int y = (t >= off) ? sh[t - off] : 0;
        __syncthreads();
        sh[t] += y;
        __syncthreads();
    }
    if (i < N) cursor[i] = sh[t] - v;
    if (t == 255) bsum[blockIdx.x] = sh[255];
}

__global__ void k_scanB(int* __restrict__ bsum, int* __restrict__ boff, int nb) {
    __shared__ int sh[256];
    int t = threadIdx.x;
    int v = (t < nb) ? bsum[t] : 0;
    sh[t] = v;
    __syncthreads();
    for (int off = 1; off < 256; off <<= 1) {
        int y = (t >= off) ? sh[t - off] : 0;
        __syncthreads();
        sh[t] += y;
        __syncthreads();
    }
    if (t < nb) boff[t] = sh[t] - v;
}

__global__ void k_scanC_inv(int* __restrict__ cursor, const int* __restrict__ boff,
                            const int* __restrict__ degin, const int* __restrict__ degout,
                            float* __restrict__ din, float* __restrict__ dout, int N) {
    int i = blockIdx.x * blockDim.x + threadIdx.x;
    if (i < N) {
        cursor[i] += boff[blockIdx.x];
        int a = degin[i]; if (a < 1) a = 1;
        int b = degout[i]; if (b < 1) b = 1;
        din[i] = rsqrtf((float)a);
        dout[i] = rsqrtf((float)b);
    }
}

// ---------------- MFMA GEMM device function (no LDS) ----------------
// C[N,M] = relu?( A[N,K](fp16) @ Wpk(packed fp16) + bias )
// A given as K/64 segments (ptr, ld in halves). Optional f32 C, up to two fp16
// mirrors with row scales, optional OUTW head (out = relu-row @ W4 + b4).

struct HSegs { const _Float16* p[3]; int ld[3]; };

template <int M, int K, bool OUTW>
__device__ void mg_dev(int bx, HSegs A, const half8* __restrict__ Wpk,
                       const float* __restrict__ bias, int relu,
                       float* __restrict__ C,
                       _Float16* __restrict__ Ch0, const float* __restrict__ ms0,
                       _Float16* __restrict__ Ch1, const float* __restrict__ ms1,
                       const float* __restrict__ W4, const float* __restrict__ b4,
                       float* __restrict__ outp, int N) {
    constexpr int NT = M / 16;
    constexpr int NKS = K / 32;
    int tid = threadIdx.x;
    int wave = tid >> 6, lane = tid & 63;
    int quad = lane >> 4, m = lane & 15;
    int row0 = bx * 64 + wave * 16;
    int rowA = row0 + m; if (rowA >= N) rowA = N - 1;
    f32x4 acc[NT];
#pragma unroll
    for (int t = 0; t < NT; t++) acc[t] = (f32x4){0.f, 0.f, 0.f, 0.f};
#pragma unroll
    for (int ks = 0; ks < NKS; ks++) {
        const _Float16* ap = A.p[ks >> 1] + (size_t)rowA * A.ld[ks >> 1] + (ks & 1) * 32 + quad * 8;
        half8 af = *(const half8*)ap;
#pragma unroll
        for (int t = 0; t < NT; t++) {
            half8 bf = Wpk[(t * NKS + ks) * 64 + lane];
            acc[t] = __builtin_amdgcn_mfma_f32_16x16x32_f16(af, bf, acc[t], 0, 0, 0);
        }
    }
    // epilogue
    float outv[NT][4];
#pragma unroll
    for (int t = 0; t < NT; t++) {
        float bv = bias ? bias[t * 16 + m] : 0.f;
#pragma unroll
        for (int r = 0; r < 4; r++) {
            float v = acc[t][r] + bv;
            if (relu) v = fmaxf(v, 0.f);
            outv[t][r] = v;
        }
    }
    if (OUTW) {
        float w40[NT], w41[NT];
#pragma unroll
        for (int t = 0; t < NT; t++) {
            w40[t] = W4[(t * 16 + m) * 2];
            w41[t] = W4[(t * 16 + m) * 2 + 1];
        }
#pragma unroll
        for (int r = 0; r < 4; r++) {
            float p0 = 0.f, p1 = 0.f;
#pragma unroll
            for (int t = 0; t < NT; t++) {
                p0 += outv[t][r] * w40[t];
                p1 += outv[t][r] * w41[t];
            }
#pragma unroll
            for (int off = 1; off < 16; off <<= 1) {
                p0 += __shfl_xor(p0, off);
                p1 += __shfl_xor(p1, off);
            }
            int row = row0 + quad * 4 + r;
            if (m == 0 && row < N) {
                outp[(size_t)row * 2 + 0] = p0 + b4[0];
                outp[(size_t)row * 2 + 1] = p1 + b4[1];
            }
        }
    }
    if (C || Ch0 || Ch1) {
#pragma unroll
        for (int r = 0; r < 4; r++) {
            int row = row0 + quad * 4 + r;
            if (row >= N) continue;
            float m0 = (Ch0 && ms0) ? ms0[row] : 1.f;
            float m1 = (Ch1 && ms1) ? ms1[row] : 1.f;
#pragma unroll
            for (int t = 0; t < NT; t++) {
                size_t off = (size_t)row * M + t * 16 + m;
                if (C)   C[off] = outv[t][r];
                if (Ch0) Ch0[off] = (_Float16)(outv[t][r] * m0);
                if (Ch1) Ch1[off] = (_Float16)(outv[t][r] * m1);
            }
        }
    }
}

// ---------------- fused kernels ----------------

// P1: hist || cvt(in_feat->fp16) || pack W1,W2,Wg1,Wg2,wc
__launch_bounds__(256)
__global__ void k_P1(const int* __restrict__ src, const int* __restrict__ dst,
                     int* __restrict__ degin, int* __restrict__ degout,
                     const float* __restrict__ in_feat, _Float16* __restrict__ ih,
                     const float* __restrict__ W1, _Float16* __restrict__ W1pk,
                     const float* __restrict__ W2, _Float16* __restrict__ W2pk,
                     const float* __restrict__ Wg1, _Float16* __restrict__ Wg1pk,
                     const float* __restrict__ Wg2, _Float16* __restrict__ Wg2pk,
                     const float* __restrict__ W3, _Float16* __restrict__ wcpk,
                     int E, int N) {
    int bx = blockIdx.x;
    if (bx < HB) { hist_dev(bx, src, dst, degin, degout, E); return; }
    bx -= HB;
    if (bx < CVB) { cvt_dev(bx, in_feat, ih, N * 128 / 8); return; }
    bx -= CVB;
    if (bx < 32) { pack_std_dev(bx, W1, W1pk, 128, 64); return; }
    bx -= 32;
    if (bx < 16) { pack_std_dev(bx, W2, W2pk, 64, 64); return; }
    bx -= 16;
    if (bx < 32) { pack_std_dev(bx, Wg1, Wg1pk, 128, 64); return; }
    bx -= 32;
    if (bx < 32) { pack_std_dev(bx, Wg2, Wg2pk, 64, 128); return; }
    bx -= 32;
    pack_wc_dev(bx, W3, wcpk);
}

// Fa: scatter || a1 (ih@W1 -> h1h fp16) || a5 (ih@Wg1 -> zh = Z*dout fp16)
__launch_bounds__(256)
__global__ void k_Fa(const int* __restrict__ src, const int* __restrict__ dst,
                     int* __restrict__ cursor, int* __restrict__ cols,
                     const _Float16* __restrict__ ih,
                     const half8* __restrict__ W1pk, const float* __restrict__ b1,
                     _Float16* __restrict__ h1h,
                     const half8* __restrict__ Wg1pk, const float* __restrict__ dout,
                     _Float16* __restrict__ zh, int E, int N) {
    int bx = blockIdx.x;
    if (bx < HB) { scatter_dev(bx, src, dst, cursor, cols, E); return; }
    bx -= HB;
    HSegs A;
    A.p[0] = ih; A.ld[0] = 128;
    A.p[1] = ih + 64; A.ld[1] = 128;
    A.p[2] = nullptr; A.ld[2] = 0;
    if (bx < GB) {
        mg_dev<64, 128, false>(bx, A, W1pk, b1, 1, nullptr, h1h, nullptr,
                               nullptr, nullptr, nullptr, nullptr, nullptr, N);
        return;
    }
    bx -= GB;
    mg_dev<64, 128, false>(bx, A, Wg1pk, nullptr, 0, nullptr, zh, dout,
                           nullptr, nullptr, nullptr, nullptr, nullptr, N);
}

// a2: h = relu(h1h@W2+b2) -> hh (fp16 h) + hbuf0 (fp16 h*din)
__launch_bounds__(256)
__global__ void k_a2(const _Float16* __restrict__ h1h, const half8* __restrict__ W2pk,
                     const float* __restrict__ b2, _Float16* __restrict__ hh,
                     _Float16* __restrict__ hscaled, const float* __restrict__ din, int N) {
    HSegs A;
    A.p[0] = h1h; A.ld[0] = 64;
    A.p[1] = nullptr; A.ld[1] = 0;
    A.p[2] = nullptr; A.ld[2] = 0;
    mg_dev<64, 64, false>(blockIdx.x, A, W2pk, b2, 1, nullptr, hh, nullptr,
                          hscaled, din, nullptr, nullptr, nullptr, N);
}

// ---------------- edge-parallel pull SpMM: 1 wave per row, fp16 ----------------

struct SpmmP {
    const half4v* xh; const half4v* fsub_h; const float* rowscale; const float* bias;
    half4v* yh0; const float* ms0; half4v* yh1; const float* ms1; int relu;
};

__launch_bounds__(256)
__global__ void k_FS(SpmmP P0, SpmmP P1, const int* __restrict__ cols,
                     const int* __restrict__ cursor, const int* __restrict__ deg, int N) {
    int bx = blockIdx.x;
    bool first = bx < SPB;
    SpmmP P = first ? P0 : P1;
    int row = (first ? bx : bx - SPB) * 4 + (threadIdx.x >> 6);
    if (row >= N) return;
    int lane = threadIdx.x & 63;
    int sub = lane >> 4, c = lane & 15;
    int end = cursor[row];
    int start = end - deg[row];
    float ax = 0.f, ay = 0.f, az = 0.f, aw = 0.f;
    for (int e = start + sub; e < end; e += 4) {
        int s = cols[e];
        half4v v = P.xh[(size_t)s * 16 + c];
        ax += (float)v.x; ay += (float)v.y; az += (float)v.z; aw += (float)v.w;
    }
    ax += __shfl_xor(ax, 16); ay += __shfl_xor(ay, 16);
    az += __shfl_xor(az, 16); aw += __shfl_xor(aw, 16);
    ax += __shfl_xor(ax, 32); ay += __shfl_xor(ay, 32);
    az += __shfl_xor(az, 32); aw += __shfl_xor(aw, 32);
    if (sub != 0) return;
    size_t oidx = (size_t)row * 16 + c;
    if (P.fsub_h) {
        float d = P.rowscale[row];
        half4v f = P.fsub_h[oidx];
        ax = (float)f.x - ax * d; ay = (float)f.y - ay * d;
        az = (float)f.z - az * d; aw = (float)f.w - aw * d;
    } else {
        if (P.rowscale) { float d = P.rowscale[row]; ax *= d; ay *= d; az *= d; aw *= d; }
        if (P.bias) {
            float4 bb = ((const float4*)P.bias)[c];
            ax += bb.x; ay += bb.y; az += bb.z; aw += bb.w;
        }
        if (P.relu) {
            ax = fmaxf(ax, 0.f); ay = fmaxf(ay, 0.f);
            az = fmaxf(az, 0.f); aw = fmaxf(aw, 0.f);
        }
    }
    if (P.yh0) {
        float mm = P.ms0 ? P.ms0[row] : 1.f;
        half4v h;
        h.x = (_Float16)(ax * mm); h.y = (_Float16)(ay * mm);
        h.z = (_Float16)(az * mm); h.w = (_Float16)(aw * mm);
        P.yh0[oidx] = h;
    }
    if (P.yh1) {
        float mm = P.ms1 ? P.ms1[row] : 1.f;
        half4v h;
        h.x = (_Float16)(ax * mm); h.y = (_Float16)(ay * mm);
        h.z = (_Float16)(az * mm); h.w = (_Float16)(aw * mm);
        P.yh1[oidx] = h;
    }
}

// F3: a3 ([hh|lh|l2h]@wc+b3 -> relu -> @W4+b4 -> out) || a6 (sgh@Wg2+bg2 -> emb)
__launch_bounds__(256)
__global__ void k_F3(const _Float16* __restrict__ hh, const _Float16* __restrict__ lh,
                     const _Float16* __restrict__ l2h, const half8* __restrict__ wcpk,
                     const float* __restrict__ b3, const float* __restrict__ W4,
                     const float* __restrict__ b4, float* __restrict__ outp,
                     const _Float16* __restrict__ sgh, const half8* __restrict__ Wg2pk,
                     const float* __restrict__ bg2, float* __restrict__ emb, int N) {
    int bx = blockIdx.x;
    if (bx < GB) {
        HSegs A;
        A.p[0] = hh; A.ld[0] = 64;
        A.p[1] = lh; A.ld[1] = 64;
        A.p[2] = l2h; A.ld[2] = 64;
        mg_dev<64, 192, true>(bx, A, wcpk, b3, 1, nullptr, nullptr, nullptr,
                              nullptr, nullptr, W4, b4, outp, N);
        return;
    }
    bx -= GB;
    HSegs A;
    A.p[0] = sgh; A.ld[0] = 64;
    A.p[1] = nullptr; A.ld[1] = 0;
    A.p[2] = nullptr; A.ld[2] = 0;
    mg_dev<128, 64, false>(bx, A, Wg2pk, bg2, 0, emb, nullptr, nullptr,
                           nullptr, nullptr, nullptr, nullptr, nullptr, N);
}

extern "C" void kernel_launch(void* const* d_in, const int* in_sizes, int n_in,
                              void* d_out, int out_size, void* d_ws, size_t ws_size,
                              hipStream_t stream) {
    const int N = NN, E = NE;
    const float* in_feat = (const float*)d_in[0];
    const int* src = (const int*)d_in[1];
    const int* dst = (const int*)d_in[2];
    const float* W1 = (const float*)d_in[3];
    const float* b1 = (const float*)d_in[4];
    const float* W2 = (const float*)d_in[5];
    const float* b2 = (const float*)d_in[6];
    const float* W3 = (const float*)d_in[7];
    const float* b3 = (const float*)d_in[8];
    const float* W4 = (const float*)d_in[9];
    const float* b4 = (const float*)d_in[10];
    const float* Wg1 = (const float*)d_in[11];
    const float* bg1 = (const float*)d_in[12];
    const float* Wg2 = (const float*)d_in[13];
    const float* bg2 = (const float*)d_in[14];

    float* out = (float*)d_out;                 // [N,2]
    float* emb = out + (size_t)N * 2;           // [N,128]

    // ---- workspace layout ----
    float* fw = (float*)d_ws;
    float* din  = fw;                      // [N]
    float* dout = din + N;                 // [N]
    int* degin  = (int*)(dout + N);        // [N]
    int* degout = degin + N;               // [N]
    int* cursor = degout + N;              // [N]
    int* cols   = cursor + N;              // [E]
    int* bsum   = cols + E;                // [256]
    int* boff   = bsum + 256;              // [256]
    _Float16* hp = (_Float16*)(boff + 256);
    _Float16* ih    = hp;                   // [N*128] fp16 in_feat
    _Float16* h1h   = ih + (size_t)128 * N; // [N*64] h1
    _Float16* hh    = h1h + (size_t)64 * N; // [N*64] h
    _Float16* hsc   = hh + (size_t)64 * N;  // [N*64] h*din
    _Float16* lh    = hsc + (size_t)64 * N; // [N*64] L1
    _Float16* lsc   = lh + (size_t)64 * N;  // [N*64] L1*din
    _Float16* l2h   = lsc + (size_t)64 * N; // [N*64] L2
    _Float16* zh    = l2h + (size_t)64 * N; // [N*64] Z*dout
    _Float16* g1h   = zh + (size_t)64 * N;  // [N*64] g1*dout
    _Float16* sgh   = g1h + (size_t)64 * N; // [N*64] SG*din
    _Float16* W1pk  = sgh + (size_t)64 * N; // 8192
    _Float16* W2pk  = W1pk + 8192;          // 4096
    _Float16* Wg1pk = W2pk + 4096;          // 8192
    _Float16* Wg2pk = Wg1pk + 8192;         // 8192
    _Float16* wcpk  = Wg2pk + 8192;         // 12288

    int nb = cdiv(N, 256);   // 196

    // 1) zero degree arrays
    k_zero_i<<<cdiv(2 * N, 256), 256, 0, stream>>>(degin, 2 * N);

    // 2) P1: hist || cvt || packs
    k_P1<<<HB + CVB + 32 + 16 + 32 + 32 + 48, 256, 0, stream>>>(
        src, dst, degin, degout, in_feat, ih,
        W1, W1pk, W2, W2pk, Wg1, Wg1pk, Wg2, Wg2pk, W3, wcpk, E, N);

    // 3) scan + degree norms
    k_scanA<<<nb, 256, 0, stream>>>(degin, cursor, bsum, N);
    k_scanB<<<1, 256, 0, stream>>>(bsum, boff, nb);
    k_scanC_inv<<<nb, 256, 0, stream>>>(cursor, boff, degin, degout, din, dout, N);

    // 4) Fa: scatter || a1 || a5
    k_Fa<<<HB + 2 * GB, 256, 0, stream>>>(src, dst, cursor, cols, ih,
        (const half8*)W1pk, b1, h1h, (const half8*)Wg1pk, dout, zh, E, N);

    // 5) a2: h
    k_a2<<<GB, 256, 0, stream>>>(h1h, (const half8*)W2pk, b2, hh, hsc, din, N);

    // 6) FS1: L1 = lap(h) [lh + lsc] || g1 = relu(spmm(zh)*din+bg1) [g1h = g1*dout]
    SpmmP p0, p1;
    p0 = {(const half4v*)hsc, (const half4v*)hh, din, nullptr,
          (half4v*)lh, nullptr, (half4v*)lsc, din, 0};
    p1 = {(const half4v*)zh, nullptr, din, bg1,
          (half4v*)g1h, dout, nullptr, nullptr, 1};
    k_FS<<<2 * SPB, 256, 0, stream>>>(p0, p1, cols, cursor, degin, N);

    // 7) FS2: L2 = lap(L1) [l2h] || SG = spmm(g1h) [sgh = SG*din]
    p0 = {(const half4v*)lsc, (const half4v*)lh, din, nullptr,
          (half4v*)l2h, nullptr, nullptr, nullptr, 0};
    p1 = {(const half4v*)g1h, nullptr, nullptr, nullptr,
          (half4v*)sgh, din, nullptr, nullptr, 0};
    k_FS<<<2 * SPB, 256, 0, stream>>>(p0, p1, cols, cursor, degin, N);

    // 8) F3: out || emb
    k_F3<<<2 * GB, 256, 0, stream>>>(hh, lh, l2h, (const half8*)wcpk, b3, W4, b4, out,
        sgh, (const half8*)Wg2pk, bg2, emb, N);
}

// Round 8
// 302.586 us; speedup vs baseline: 1.4337x; 1.2356x over previous
//
#include <hip/hip_runtime.h>
#include <hip/hip_bf16.h>
#include <math.h>

#define NN 50000
#define NE 800000
#define HB 782      // hist+scatter blocks (1024 edges each)
#define GB 782      // cdiv(N,64) — MFMA gemm blocks (64 rows/block)
#define ZB 391      // zero blocks in k_init
#define ZSB 782     // zscale blocks (16 halves/thread)
#define SPB 12500   // cdiv(N,4) — spmm blocks (4 rows/block, 1 wave/row)

typedef _Float16 half8 __attribute__((ext_vector_type(8)));
typedef _Float16 half4v __attribute__((ext_vector_type(4)));
typedef float f32x4 __attribute__((ext_vector_type(4)));

static inline int cdiv(int a, int b) { return (a + b - 1) / b; }

// ---------------- helpers ----------------

// fused hist + padded-CSR scatter: one atomic pass
__device__ void histscat_dev(int bx, const int* __restrict__ src, const int* __restrict__ dst,
                             int* __restrict__ degin, int* __restrict__ degout,
                             int* __restrict__ colsPad, int E) {
    int idx = bx * 256 + threadIdx.x;
    int nthr = HB * 256;
#pragma unroll
    for (int j = 0; j < 4; j++) {
        int e = idx + j * nthr;
        if (e < E) {
            int d = dst[e], s = src[e];
            int p = atomicAdd(&degin[d], 1);
            if (p < 64) colsPad[d * 64 + p] = s;
            atomicAdd(&degout[s], 1);
        }
    }
}

// B-frag pack position for MFMA 16x16x32: W[k][n] (K x M, row-major)
__device__ inline size_t pack_pos(int k, int n, int K, int M) {
    int tile = n >> 4;
    int kstep = k >> 5;
    int quad = (k >> 3) & 3;
    int j = k & 7;
    int lane = (quad << 4) | (n & 15);
    return ((size_t)(tile * (K >> 5) + kstep) * 64 + lane) * 8 + j;
}

__device__ void pack_std_dev(int bx, const float* __restrict__ W, _Float16* __restrict__ Wpk,
                             int K, int M) {
    int idx = bx * 256 + threadIdx.x;
    if (idx >= K * M) return;
    int k = idx / M, n = idx % M;
    Wpk[pack_pos(k, n, K, M)] = (_Float16)W[idx];
}

__device__ void pack_wc_dev(int bx, const float* __restrict__ W3, _Float16* __restrict__ wcpk) {
    int idx = bx * 256 + threadIdx.x;
    if (idx >= 3 * 4096) return;
    int b = idx >> 12;
    int rem = idx & 4095;
    int k = rem >> 6, n = rem & 63;
    float w0 = W3[(0 * 64 + k) * 64 + n];
    float w1 = W3[(1 * 64 + k) * 64 + n];
    float w2 = W3[(2 * 64 + k) * 64 + n];
    float w3 = W3[(3 * 64 + k) * 64 + n];
    float w4 = W3[(4 * 64 + k) * 64 + n];
    float v;
    if (b == 0)      v = 3.f * w0;
    else if (b == 1) v = -3.f * w0 + 3.f * w1 + w3;
    else             v = 0.75f * w0 - 1.5f * w1 + 0.75f * w2 + w4;
    wcpk[pack_pos(b * 64 + k, n, 192, 64)] = (_Float16)v;
}

// k_init: zero degree arrays || pack all weights   (no intra-launch deps)
__launch_bounds__(256)
__global__ void k_init(int* __restrict__ degzero,
                       const float* __restrict__ W1, _Float16* __restrict__ W1pk,
                       const float* __restrict__ W2, _Float16* __restrict__ W2pk,
                       const float* __restrict__ Wg1, _Float16* __restrict__ Wg1pk,
                       const float* __restrict__ Wg2, _Float16* __restrict__ Wg2pk,
                       const float* __restrict__ W3, _Float16* __restrict__ wcpk,
                       int nzero) {
    int bx = blockIdx.x;
    if (bx < ZB) {
        int i = bx * 256 + threadIdx.x;
        if (i < nzero) degzero[i] = 0;
        return;
    }
    bx -= ZB;
    if (bx < 32) { pack_std_dev(bx, W1, W1pk, 128, 64); return; }
    bx -= 32;
    if (bx < 16) { pack_std_dev(bx, W2, W2pk, 64, 64); return; }
    bx -= 16;
    if (bx < 32) { pack_std_dev(bx, Wg1, Wg1pk, 128, 64); return; }
    bx -= 32;
    if (bx < 32) { pack_std_dev(bx, Wg2, Wg2pk, 64, 128); return; }
    bx -= 32;
    pack_wc_dev(bx, W3, wcpk);
}

__global__ void k_dinout(const int* __restrict__ degin, const int* __restrict__ degout,
                         float* __restrict__ din, float* __restrict__ dout, int N) {
    int i = blockIdx.x * blockDim.x + threadIdx.x;
    if (i < N) {
        int a = degin[i]; if (a < 1) a = 1;
        int b = degout[i]; if (b < 1) b = 1;
        din[i] = rsqrtf((float)a);
        dout[i] = rsqrtf((float)b);
    }
}

// zh *= dout (16 halves/thread)
__device__ void zscale_dev(int bx, half8* __restrict__ zh8, const float* __restrict__ dout, int N) {
    int idx = bx * 256 + threadIdx.x;
    if (idx >= N * 4) return;
    int row = idx >> 2;
    float m = dout[row];
    half8 a = zh8[idx * 2], b = zh8[idx * 2 + 1];
#pragma unroll
    for (int j = 0; j < 8; j++) {
        a[j] = (_Float16)((float)a[j] * m);
        b[j] = (_Float16)((float)b[j] * m);
    }
    zh8[idx * 2] = a; zh8[idx * 2 + 1] = b;
}

// ---------------- MFMA GEMM device function (no LDS) ----------------

struct HSegs { const void* p[3]; int ld[3]; };

template <int M, int K, bool OUTW, bool F32A>
__device__ void mg_dev(int bx, HSegs A, const half8* __restrict__ Wpk,
                       const float* __restrict__ bias, int relu,
                       float* __restrict__ C,
                       _Float16* __restrict__ Ch0, const float* __restrict__ ms0,
                       _Float16* __restrict__ Ch1, const float* __restrict__ ms1,
                       const float* __restrict__ W4, const float* __restrict__ b4,
                       float* __restrict__ outp, int N) {
    constexpr int NT = M / 16;
    constexpr int NKS = K / 32;
    int tid = threadIdx.x;
    int wave = tid >> 6, lane = tid & 63;
    int quad = lane >> 4, m = lane & 15;
    int row0 = bx * 64 + wave * 16;
    int rowA = row0 + m; if (rowA >= N) rowA = N - 1;
    f32x4 acc[NT];
#pragma unroll
    for (int t = 0; t < NT; t++) acc[t] = (f32x4){0.f, 0.f, 0.f, 0.f};
#pragma unroll
    for (int ks = 0; ks < NKS; ks++) {
        half8 af;
        if (F32A) {
            const float* ap = (const float*)A.p[ks >> 1] + (size_t)rowA * A.ld[ks >> 1] + (ks & 1) * 32 + quad * 8;
            float4 u = *(const float4*)ap;
            float4 v = *(const float4*)(ap + 4);
            af[0] = (_Float16)u.x; af[1] = (_Float16)u.y; af[2] = (_Float16)u.z; af[3] = (_Float16)u.w;
            af[4] = (_Float16)v.x; af[5] = (_Float16)v.y; af[6] = (_Float16)v.z; af[7] = (_Float16)v.w;
        } else {
            const _Float16* ap = (const _Float16*)A.p[ks >> 1] + (size_t)rowA * A.ld[ks >> 1] + (ks & 1) * 32 + quad * 8;
            af = *(const half8*)ap;
        }
#pragma unroll
        for (int t = 0; t < NT; t++) {
            half8 bf = Wpk[(t * NKS + ks) * 64 + lane];
            acc[t] = __builtin_amdgcn_mfma_f32_16x16x32_f16(af, bf, acc[t], 0, 0, 0);
        }
    }
    float outv[NT][4];
#pragma unroll
    for (int t = 0; t < NT; t++) {
        float bv = bias ? bias[t * 16 + m] : 0.f;
#pragma unroll
        for (int r = 0; r < 4; r++) {
            float v = acc[t][r] + bv;
            if (relu) v = fmaxf(v, 0.f);
            outv[t][r] = v;
        }
    }
    if (OUTW) {
        float w40[NT], w41[NT];
#pragma unroll
        for (int t = 0; t < NT; t++) {
            w40[t] = W4[(t * 16 + m) * 2];
            w41[t] = W4[(t * 16 + m) * 2 + 1];
        }
#pragma unroll
        for (int r = 0; r < 4; r++) {
            float p0 = 0.f, p1 = 0.f;
#pragma unroll
            for (int t = 0; t < NT; t++) {
                p0 += outv[t][r] * w40[t];
                p1 += outv[t][r] * w41[t];
            }
#pragma unroll
            for (int off = 1; off < 16; off <<= 1) {
                p0 += __shfl_xor(p0, off);
                p1 += __shfl_xor(p1, off);
            }
            int row = row0 + quad * 4 + r;
            if (m == 0 && row < N) {
                outp[(size_t)row * 2 + 0] = p0 + b4[0];
                outp[(size_t)row * 2 + 1] = p1 + b4[1];
            }
        }
    }
    if (C || Ch0 || Ch1) {
#pragma unroll
        for (int r = 0; r < 4; r++) {
            int row = row0 + quad * 4 + r;
            if (row >= N) continue;
            float m0 = (Ch0 && ms0) ? ms0[row] : 1.f;
            float m1 = (Ch1 && ms1) ? ms1[row] : 1.f;
#pragma unroll
            for (int t = 0; t < NT; t++) {
                size_t off = (size_t)row * M + t * 16 + m;
                if (C)   C[off] = outv[t][r];
                if (Ch0) Ch0[off] = (_Float16)(outv[t][r] * m0);
                if (Ch1) Ch1[off] = (_Float16)(outv[t][r] * m1);
            }
        }
    }
}

// ---------------- fused kernels ----------------

// P1: hist+scatter(padded CSR) || a1 (in_feat@W1 -> h1h) || a5 (in_feat@Wg1 -> zh unscaled)
// (weights packed in k_init, one launch earlier — no intra-launch dependency)
__launch_bounds__(256)
__global__ void k_P1(const int* __restrict__ src, const int* __restrict__ dst,
                     int* __restrict__ degin, int* __restrict__ degout,
                     int* __restrict__ colsPad,
                     const float* __restrict__ in_feat,
                     const half8* __restrict__ W1pk, const half8* __restrict__ Wg1pk,
                     const float* __restrict__ b1,
                     _Float16* __restrict__ h1h, _Float16* __restrict__ zh,
                     int E, int N) {
    int bx = blockIdx.x;
    if (bx < HB) { histscat_dev(bx, src, dst, degin, degout, colsPad, E); return; }
    bx -= HB;
    HSegs A;
    A.p[0] = in_feat; A.ld[0] = 128;
    A.p[1] = in_feat + 64; A.ld[1] = 128;
    A.p[2] = nullptr; A.ld[2] = 0;
    if (bx < GB) {
        mg_dev<64, 128, false, true>(bx, A, W1pk, b1, 1, nullptr, h1h, nullptr,
                                     nullptr, nullptr, nullptr, nullptr, nullptr, N);
        return;
    }
    bx -= GB;
    mg_dev<64, 128, false, true>(bx, A, Wg1pk, nullptr, 0, nullptr, zh, nullptr,
                                 nullptr, nullptr, nullptr, nullptr, nullptr, N);
}

// Fa: a2 (h1h@W2 -> hh fp16 + hsc fp16 h*din) || zscale (zh *= dout)
__launch_bounds__(256)
__global__ void k_Fa(const _Float16* __restrict__ h1h, const half8* __restrict__ W2pk,
                     const float* __restrict__ b2, _Float16* __restrict__ hh,
                     _Float16* __restrict__ hsc, const float* __restrict__ din,
                     half8* __restrict__ zh8, const float* __restrict__ dout, int N) {
    int bx = blockIdx.x;
    if (bx < GB) {
        HSegs A;
        A.p[0] = h1h; A.ld[0] = 64;
        A.p[1] = nullptr; A.ld[1] = 0;
        A.p[2] = nullptr; A.ld[2] = 0;
        mg_dev<64, 64, false, false>(bx, A, W2pk, b2, 1, nullptr, hh, nullptr,
                                     hsc, din, nullptr, nullptr, nullptr, N);
        return;
    }
    bx -= GB;
    zscale_dev(bx, zh8, dout, N);
}

// ---------------- edge-parallel pull SpMM over padded CSR: 1 wave/row ----------------

struct SpmmP {
    const half4v* xh; const half4v* fsub_h; const float* rowscale; const float* bias;
    half4v* yh0; const float* ms0; half4v* yh1; const float* ms1; int relu;
};

__launch_bounds__(256)
__global__ void k_FS(SpmmP P0, SpmmP P1, const int* __restrict__ colsPad,
                     const int* __restrict__ deg, int N) {
    int bx = blockIdx.x;
    bool first = bx < SPB;
    SpmmP P = first ? P0 : P1;
    int row = (first ? bx : bx - SPB) * 4 + (threadIdx.x >> 6);
    if (row >= N) return;
    int lane = threadIdx.x & 63;
    int sub = lane >> 4, c = lane & 15;
    int dg = deg[row]; if (dg > 64) dg = 64;
    int base = row * 64;
    int e = base + sub;
    int end = base + dg;
    float ax = 0.f, ay = 0.f, az = 0.f, aw = 0.f;
    for (; e + 12 < end; e += 16) {
        int s0 = colsPad[e], s1 = colsPad[e + 4], s2 = colsPad[e + 8], s3 = colsPad[e + 12];
        half4v v0 = P.xh[(size_t)s0 * 16 + c];
        half4v v1 = P.xh[(size_t)s1 * 16 + c];
        half4v v2 = P.xh[(size_t)s2 * 16 + c];
        half4v v3 = P.xh[(size_t)s3 * 16 + c];
        ax += (float)v0.x + (float)v1.x + (float)v2.x + (float)v3.x;
        ay += (float)v0.y + (float)v1.y + (float)v2.y + (float)v3.y;
        az += (float)v0.z + (float)v1.z + (float)v2.z + (float)v3.z;
        aw += (float)v0.w + (float)v1.w + (float)v2.w + (float)v3.w;
    }
    for (; e < end; e += 4) {
        int s = colsPad[e];
        half4v v = P.xh[(size_t)s * 16 + c];
        ax += (float)v.x; ay += (float)v.y; az += (float)v.z; aw += (float)v.w;
    }
    ax += __shfl_xor(ax, 16); ay += __shfl_xor(ay, 16);
    az += __shfl_xor(az, 16); aw += __shfl_xor(aw, 16);
    ax += __shfl_xor(ax, 32); ay += __shfl_xor(ay, 32);
    az += __shfl_xor(az, 32); aw += __shfl_xor(aw, 32);
    if (sub != 0) return;
    size_t oidx = (size_t)row * 16 + c;
    if (P.fsub_h) {
        float d = P.rowscale[row];
        half4v f = P.fsub_h[oidx];
        ax = (float)f.x - ax * d; ay = (float)f.y - ay * d;
        az = (float)f.z - az * d; aw = (float)f.w - aw * d;
    } else {
        if (P.rowscale) { float d = P.rowscale[row]; ax *= d; ay *= d; az *= d; aw *= d; }
        if (P.bias) {
            float4 bb = ((const float4*)P.bias)[c];
            ax += bb.x; ay += bb.y; az += bb.z; aw += bb.w;
        }
        if (P.relu) {
            ax = fmaxf(ax, 0.f); ay = fmaxf(ay, 0.f);
            az = fmaxf(az, 0.f); aw = fmaxf(aw, 0.f);
        }
    }
    if (P.yh0) {
        float mm = P.ms0 ? P.ms0[row] : 1.f;
        half4v h;
        h.x = (_Float16)(ax * mm); h.y = (_Float16)(ay * mm);
        h.z = (_Float16)(az * mm); h.w = (_Float16)(aw * mm);
        P.yh0[oidx] = h;
    }
    if (P.yh1) {
        float mm = P.ms1 ? P.ms1[row] : 1.f;
        half4v h;
        h.x = (_Float16)(ax * mm); h.y = (_Float16)(ay * mm);
        h.z = (_Float16)(az * mm); h.w = (_Float16)(aw * mm);
        P.yh1[oidx] = h;
    }
}

// F3: a3 ([hh|lh|l2h]@wc+b3 -> relu -> @W4+b4 -> out) || a6 (sgh@Wg2+bg2 -> emb)
__launch_bounds__(256)
__global__ void k_F3(const _Float16* __restrict__ hh, const _Float16* __restrict__ lh,
                     const _Float16* __restrict__ l2h, const half8* __restrict__ wcpk,
                     const float* __restrict__ b3, const float* __restrict__ W4,
                     const float* __restrict__ b4, float* __restrict__ outp,
                     const _Float16* __restrict__ sgh, const half8* __restrict__ Wg2pk,
                     const float* __restrict__ bg2, float* __restrict__ emb, int N) {
    int bx = blockIdx.x;
    if (bx < GB) {
        HSegs A;
        A.p[0] = hh; A.ld[0] = 64;
        A.p[1] = lh; A.ld[1] = 64;
        A.p[2] = l2h; A.ld[2] = 64;
        mg_dev<64, 192, true, false>(bx, A, wcpk, b3, 1, nullptr, nullptr, nullptr,
                                     nullptr, nullptr, W4, b4, outp, N);
        return;
    }
    bx -= GB;
    HSegs A;
    A.p[0] = sgh; A.ld[0] = 64;
    A.p[1] = nullptr; A.ld[1] = 0;
    A.p[2] = nullptr; A.ld[2] = 0;
    mg_dev<128, 64, false, false>(bx, A, Wg2pk, bg2, 0, emb, nullptr, nullptr,
                                  nullptr, nullptr, nullptr, nullptr, nullptr, N);
}

extern "C" void kernel_launch(void* const* d_in, const int* in_sizes, int n_in,
                              void* d_out, int out_size, void* d_ws, size_t ws_size,
                              hipStream_t stream) {
    const int N = NN, E = NE;
    const float* in_feat = (const float*)d_in[0];
    const int* src = (const int*)d_in[1];
    const int* dst = (const int*)d_in[2];
    const float* W1 = (const float*)d_in[3];
    const float* b1 = (const float*)d_in[4];
    const float* W2 = (const float*)d_in[5];
    const float* b2 = (const float*)d_in[6];
    const float* W3 = (const float*)d_in[7];
    const float* b3 = (const float*)d_in[8];
    const float* W4 = (const float*)d_in[9];
    const float* b4 = (const float*)d_in[10];
    const float* Wg1 = (const float*)d_in[11];
    const float* bg1 = (const float*)d_in[12];
    const float* Wg2 = (const float*)d_in[13];
    const float* bg2 = (const float*)d_in[14];

    float* out = (float*)d_out;                 // [N,2]
    float* emb = out + (size_t)N * 2;           // [N,128]

    // ---- workspace layout ----
    float* fw = (float*)d_ws;
    float* din  = fw;                      // [N]
    float* dout = din + N;                 // [N]
    int* degin  = (int*)(dout + N);        // [N]
    int* degout = degin + N;               // [N]  (contiguous with degin for zeroing)
    int* colsPad = degout + N;             // [N*64]
    _Float16* hp = (_Float16*)(colsPad + (size_t)64 * N);
    _Float16* h1h   = hp;                   // [N*64] h1
    _Float16* hh    = h1h + (size_t)64 * N; // [N*64] h
    _Float16* hsc   = hh + (size_t)64 * N;  // [N*64] h*din
    _Float16* lh    = hsc + (size_t)64 * N; // [N*64] L1
    _Float16* lsc   = lh + (size_t)64 * N;  // [N*64] L1*din
    _Float16* l2h   = lsc + (size_t)64 * N; // [N*64] L2
    _Float16* zh    = l2h + (size_t)64 * N; // [N*64] Z (later *dout)
    _Float16* g1h   = zh + (size_t)64 * N;  // [N*64] g1*dout
    _Float16* sgh   = g1h + (size_t)64 * N; // [N*64] SG*din
    _Float16* W1pk  = sgh + (size_t)64 * N; // 8192
    _Float16* W2pk  = W1pk + 8192;          // 4096
    _Float16* Wg1pk = W2pk + 4096;          // 8192
    _Float16* Wg2pk = Wg1pk + 8192;         // 8192
    _Float16* wcpk  = Wg2pk + 8192;         // 12288

    // 1) init: zero degrees || pack all weights  (packs one launch BEFORE any GEMM)
    k_init<<<ZB + 160, 256, 0, stream>>>(degin,
        W1, W1pk, W2, W2pk, Wg1, Wg1pk, Wg2, Wg2pk, W3, wcpk, 2 * N);

    // 2) P1: hist+scatter || a1 || a5
    k_P1<<<HB + 2 * GB, 256, 0, stream>>>(
        src, dst, degin, degout, colsPad, in_feat,
        (const half8*)W1pk, (const half8*)Wg1pk, b1, h1h, zh, E, N);

    // 3) din/dout
    k_dinout<<<cdiv(N, 256), 256, 0, stream>>>(degin, degout, din, dout, N);

    // 4) Fa: a2 || zscale
    k_Fa<<<GB + ZSB, 256, 0, stream>>>(h1h, (const half8*)W2pk, b2, hh, hsc, din,
        (half8*)zh, dout, N);

    // 5) FS1: L1 = lap(h) [lh + lsc=L1*din] || g1 = relu(spmm(zh)*din+bg1) [g1h=g1*dout]
    SpmmP p0, p1;
    p0 = {(const half4v*)hsc, (const half4v*)hh, din, nullptr,
          (half4v*)lh, nullptr, (half4v*)lsc, din, 0};
    p1 = {(const half4v*)zh, nullptr, din, bg1,
          (half4v*)g1h, dout, nullptr, nullptr, 1};
    k_FS<<<2 * SPB, 256, 0, stream>>>(p0, p1, colsPad, degin, N);

    // 6) FS2: L2 = lap(L1) [l2h] || SG = spmm(g1h) [sgh=SG*din]
    p0 = {(const half4v*)lsc, (const half4v*)lh, din, nullptr,
          (half4v*)l2h, nullptr, nullptr, nullptr, 0};
    p1 = {(const half4v*)g1h, nullptr, nullptr, nullptr,
          (half4v*)sgh, din, nullptr, nullptr, 0};
    k_FS<<<2 * SPB, 256, 0, stream>>>(p0, p1, colsPad, degin, N);

    // 7) F3: out || emb
    k_F3<<<2 * GB, 256, 0, stream>>>(hh, lh, l2h, (const half8*)wcpk, b3, W4, b4, out,
        sgh, (const half8*)Wg2pk, bg2, emb, N);
}

// Round 9
// 293.605 us; speedup vs baseline: 1.4776x; 1.0306x over previous
//
#include <hip/hip_runtime.h>
#include <hip/hip_bf16.h>
#include <math.h>

#define NN 50000
#define NE 800000
#define C64 64        // edge chunks
#define CE 12500      // edges per chunk (NE/C64)
#define RW 12500      // packed u32 words per node range (25000 nodes)
#define NW 25000      // total packed words (NN/2)
#define HISTB 128     // hist blocks per direction (64 chunks x 2 ranges)
#define RB 98         // cdiv(NW,256)
#define GB 782        // cdiv(NN,64)
#define ZSB 782
#define SPB 12500     // cdiv(NN,4)

typedef _Float16 half8 __attribute__((ext_vector_type(8)));
typedef _Float16 half4v __attribute__((ext_vector_type(4)));
typedef float f32x4 __attribute__((ext_vector_type(4)));

static inline int cdiv(int a, int b) { return (a + b - 1) / b; }

// ---------------- weight packing ----------------

// B-frag pack position for MFMA 16x16x32: W[k][n] (K x M, row-major)
__device__ inline size_t pack_pos(int k, int n, int K, int M) {
    int tile = n >> 4;
    int kstep = k >> 5;
    int quad = (k >> 3) & 3;
    int j = k & 7;
    int lane = (quad << 4) | (n & 15);
    return ((size_t)(tile * (K >> 5) + kstep) * 64 + lane) * 8 + j;
}

__device__ void pack_std_dev(int bx, const float* __restrict__ W, _Float16* __restrict__ Wpk,
                             int K, int M) {
    int idx = bx * 256 + threadIdx.x;
    if (idx >= K * M) return;
    int k = idx / M, n = idx % M;
    Wpk[pack_pos(k, n, K, M)] = (_Float16)W[idx];
}

__device__ void pack_wc_dev(int bx, const float* __restrict__ W3, _Float16* __restrict__ wcpk) {
    int idx = bx * 256 + threadIdx.x;
    if (idx >= 3 * 4096) return;
    int b = idx >> 12;
    int rem = idx & 4095;
    int k = rem >> 6, n = rem & 63;
    float w0 = W3[(0 * 64 + k) * 64 + n];
    float w1 = W3[(1 * 64 + k) * 64 + n];
    float w2 = W3[(2 * 64 + k) * 64 + n];
    float w3 = W3[(3 * 64 + k) * 64 + n];
    float w4 = W3[(4 * 64 + k) * 64 + n];
    float v;
    if (b == 0)      v = 3.f * w0;
    else if (b == 1) v = -3.f * w0 + 3.f * w1 + w3;
    else             v = 0.75f * w0 - 1.5f * w1 + 0.75f * w2 + w4;
    wcpk[pack_pos(b * 64 + k, n, 192, 64)] = (_Float16)v;
}

// k_init: pack all weights (no other deps; must precede every GEMM launch)
__launch_bounds__(256)
__global__ void k_init(const float* __restrict__ W1, _Float16* __restrict__ W1pk,
                       const float* __restrict__ W2, _Float16* __restrict__ W2pk,
                       const float* __restrict__ Wg1, _Float16* __restrict__ Wg1pk,
                       const float* __restrict__ Wg2, _Float16* __restrict__ Wg2pk,
                       const float* __restrict__ W3, _Float16* __restrict__ wcpk) {
    int bx = blockIdx.x;
    if (bx < 32) { pack_std_dev(bx, W1, W1pk, 128, 64); return; }
    bx -= 32;
    if (bx < 16) { pack_std_dev(bx, W2, W2pk, 64, 64); return; }
    bx -= 16;
    if (bx < 32) { pack_std_dev(bx, Wg1, Wg1pk, 128, 64); return; }
    bx -= 32;
    if (bx < 32) { pack_std_dev(bx, Wg2, Wg2pk, 64, 128); return; }
    bx -= 32;
    pack_wc_dev(bx, W3, wcpk);
}

// ---------------- atomic-free CSR build ----------------

// per-chunk, per-range LDS histogram (u16 pairs packed in u32)
__device__ void hist_dev(int bx, const int* __restrict__ idx, unsigned* __restrict__ H,
                         unsigned* __restrict__ cnt) {
    int c = bx & 63, r = bx >> 6;
    int tid = threadIdx.x;
    for (int j = tid; j < RW; j += 256) cnt[j] = 0;
    __syncthreads();
    int lo = r * 25000;
    const int* p = idx + c * CE;
    for (int i = tid; i < CE; i += 256) {
        int v = p[i] - lo;
        if ((unsigned)v < 25000u)
            atomicAdd(&cnt[v >> 1], 1u << ((v & 1) * 16));
    }
    __syncthreads();
    unsigned* outp = H + (size_t)c * NW + r * RW;
    for (int j = tid; j < RW; j += 256) outp[j] = cnt[j];
}

// reduce partials -> degrees + norms (streaming, no atomics)
__device__ void reduce_dev(int bx, const unsigned* __restrict__ H, int* __restrict__ dgo,
                           float* __restrict__ o_rsq, float* __restrict__ o_inv,
                           float* __restrict__ o_sq) {
    int w = bx * 256 + threadIdx.x;
    if (w >= NW) return;
    unsigned slo = 0, shi = 0;
#pragma unroll 8
    for (int c = 0; c < 64; c++) {
        unsigned h = H[(size_t)c * NW + w];
        slo += h & 0xffffu; shi += h >> 16;
    }
    if (dgo) {
        dgo[2 * w]     = slo > 64u ? 64 : (int)slo;
        dgo[2 * w + 1] = shi > 64u ? 64 : (int)shi;
    }
    float f0 = (float)(slo < 1u ? 1u : slo);
    float f1 = (float)(shi < 1u ? 1u : shi);
    o_rsq[2 * w] = rsqrtf(f0); o_rsq[2 * w + 1] = rsqrtf(f1);
    if (o_inv) { o_inv[2 * w] = 1.f / f0; o_inv[2 * w + 1] = 1.f / f1; }
    if (o_sq)  { o_sq[2 * w] = sqrtf(f0); o_sq[2 * w + 1] = sqrtf(f1); }
}

// per-chunk exclusive prefix of dst partials -> scatter bases (u16 pairs)
__device__ void prefix_dev(int bx, const unsigned* __restrict__ HD, unsigned* __restrict__ baseD) {
    int w = bx * 256 + threadIdx.x;
    if (w >= NW) return;
    unsigned slo = 0, shi = 0;
    for (int c = 0; c < 64; c++) {
        unsigned b0 = slo > 64u ? 64u : slo;
        unsigned b1 = shi > 64u ? 64u : shi;
        baseD[(size_t)c * NW + w] = b0 | (b1 << 16);
        unsigned h = HD[(size_t)c * NW + w];
        slo += h & 0xffffu; shi += h >> 16;
    }
}

// deterministic scatter: LDS intra-chunk ranks + precomputed bases, no global atomics
__device__ void scatter_dev(int bx, const int* __restrict__ src, const int* __restrict__ dst,
                            const unsigned* __restrict__ baseD, int* __restrict__ colsPad,
                            unsigned* __restrict__ cnt) {
    int c = bx & 63, r = bx >> 6;
    int tid = threadIdx.x;
    for (int j = tid; j < RW; j += 256) cnt[j] = 0;
    __syncthreads();
    int lo = r * 25000;
    const int* pd = dst + c * CE;
    const int* ps = src + c * CE;
    for (int i = tid; i < CE; i += 256) {
        int v = pd[i];
        int lv = v - lo;
        if ((unsigned)lv < 25000u) {
            unsigned old = atomicAdd(&cnt[lv >> 1], 1u << ((lv & 1) * 16));
            unsigned rank = (old >> ((lv & 1) * 16)) & 0xffffu;
            unsigned base = (baseD[(size_t)c * NW + (v >> 1)] >> ((v & 1) * 16)) & 0xffffu;
            unsigned pos = base + rank;
            if (pos < 64u) colsPad[(size_t)v * 64 + pos] = ps[i];
        }
    }
}

// zh *= dout (16 halves/thread)
__device__ void zscale_dev(int bx, half8* __restrict__ zh8, const float* __restrict__ dout, int N) {
    int idx = bx * 256 + threadIdx.x;
    if (idx >= N * 4) return;
    int row = idx >> 2;
    float m = dout[row];
    half8 a = zh8[idx * 2], b = zh8[idx * 2 + 1];
#pragma unroll
    for (int j = 0; j < 8; j++) {
        a[j] = (_Float16)((float)a[j] * m);
        b[j] = (_Float16)((float)b[j] * m);
    }
    zh8[idx * 2] = a; zh8[idx * 2 + 1] = b;
}

// ---------------- MFMA GEMM device functions (no LDS) ----------------

struct HSegs { const _Float16* p[3]; int ld[3]; };

// generic: C = relu?(A@Wpk + bias); A rows optionally scaled by rsc[row] (RSCA);
// optional fp16 mirror Ch0 = half(C*ms0); optional OUTW head -> outp[row,0:2]
template <int M, int K, bool OUTW, bool RSCA>
__device__ void mg_dev(int bx, HSegs A, const half8* __restrict__ Wpk,
                       const float* __restrict__ bias, int relu,
                       float* __restrict__ C,
                       _Float16* __restrict__ Ch0, const float* __restrict__ ms0,
                       const float* __restrict__ rsc,
                       const float* __restrict__ W4, const float* __restrict__ b4,
                       float* __restrict__ outp, int N) {
    constexpr int NT = M / 16;
    constexpr int NKS = K / 32;
    int tid = threadIdx.x;
    int wave = tid >> 6, lane = tid & 63;
    int quad = lane >> 4, m = lane & 15;
    int row0 = bx * 64 + wave * 16;
    int rowA = row0 + m; if (rowA >= N) rowA = N - 1;
    _Float16 hs = (_Float16)1.f;
    if (RSCA) hs = (_Float16)rsc[rowA];
    f32x4 acc[NT];
#pragma unroll
    for (int t = 0; t < NT; t++) acc[t] = (f32x4){0.f, 0.f, 0.f, 0.f};
#pragma unroll
    for (int ks = 0; ks < NKS; ks++) {
        const _Float16* ap = A.p[ks >> 1] + (size_t)rowA * A.ld[ks >> 1] + (ks & 1) * 32 + quad * 8;
        half8 af = *(const half8*)ap;
        if (RSCA) {
#pragma unroll
            for (int j = 0; j < 8; j++) af[j] *= hs;
        }
#pragma unroll
        for (int t = 0; t < NT; t++) {
            half8 bf = Wpk[(t * NKS + ks) * 64 + lane];
            acc[t] = __builtin_amdgcn_mfma_f32_16x16x32_f16(af, bf, acc[t], 0, 0, 0);
        }
    }
    float outv[NT][4];
#pragma unroll
    for (int t = 0; t < NT; t++) {
        float bv = bias ? bias[t * 16 + m] : 0.f;
#pragma unroll
        for (int r = 0; r < 4; r++) {
            float v = acc[t][r] + bv;
            if (relu) v = fmaxf(v, 0.f);
            outv[t][r] = v;
        }
    }
    if (OUTW) {
        float w40[NT], w41[NT];
#pragma unroll
        for (int t = 0; t < NT; t++) {
            w40[t] = W4[(t * 16 + m) * 2];
            w41[t] = W4[(t * 16 + m) * 2 + 1];
        }
#pragma unroll
        for (int r = 0; r < 4; r++) {
            float p0 = 0.f, p1 = 0.f;
#pragma unroll
            for (int t = 0; t < NT; t++) {
                p0 += outv[t][r] * w40[t];
                p1 += outv[t][r] * w41[t];
            }
#pragma unroll
            for (int off = 1; off < 16; off <<= 1) {
                p0 += __shfl_xor(p0, off);
                p1 += __shfl_xor(p1, off);
            }
            int row = row0 + quad * 4 + r;
            if (m == 0 && row < N) {
                outp[(size_t)row * 2 + 0] = p0 + b4[0];
                outp[(size_t)row * 2 + 1] = p1 + b4[1];
            }
        }
    }
    if (C || Ch0) {
#pragma unroll
        for (int r = 0; r < 4; r++) {
            int row = row0 + quad * 4 + r;
            if (row >= N) continue;
            float m0 = (Ch0 && ms0) ? ms0[row] : 1.f;
#pragma unroll
            for (int t = 0; t < NT; t++) {
                size_t off = (size_t)row * M + t * 16 + m;
                if (C)   C[off] = outv[t][r];
                if (Ch0) Ch0[off] = (_Float16)(outv[t][r] * m0);
            }
        }
    }
}

// fused a1+a5: shared A-fragments (f32 in_feat -> fp16), two B matrices
__device__ void a15_dev(int bx, const float* __restrict__ in_feat,
                        const half8* __restrict__ W1pk, const half8* __restrict__ Wg1pk,
                        const float* __restrict__ b1,
                        _Float16* __restrict__ h1h, _Float16* __restrict__ zh, int N) {
    int tid = threadIdx.x;
    int wave = tid >> 6, lane = tid & 63;
    int quad = lane >> 4, m = lane & 15;
    int row0 = bx * 64 + wave * 16;
    int rowA = row0 + m; if (rowA >= N) rowA = N - 1;
    f32x4 acc0[4], acc1[4];
#pragma unroll
    for (int t = 0; t < 4; t++) {
        acc0[t] = (f32x4){0.f, 0.f, 0.f, 0.f};
        acc1[t] = (f32x4){0.f, 0.f, 0.f, 0.f};
    }
#pragma unroll
    for (int ks = 0; ks < 4; ks++) {
        const float* ap = in_feat + (size_t)rowA * 128 + ks * 32 + quad * 8;
        float4 u = *(const float4*)ap;
        float4 v = *(const float4*)(ap + 4);
        half8 af;
        af[0] = (_Float16)u.x; af[1] = (_Float16)u.y; af[2] = (_Float16)u.z; af[3] = (_Float16)u.w;
        af[4] = (_Float16)v.x; af[5] = (_Float16)v.y; af[6] = (_Float16)v.z; af[7] = (_Float16)v.w;
#pragma unroll
        for (int t = 0; t < 4; t++) {
            acc0[t] = __builtin_amdgcn_mfma_f32_16x16x32_f16(af, W1pk[(t * 4 + ks) * 64 + lane], acc0[t], 0, 0, 0);
            acc1[t] = __builtin_amdgcn_mfma_f32_16x16x32_f16(af, Wg1pk[(t * 4 + ks) * 64 + lane], acc1[t], 0, 0, 0);
        }
    }
#pragma unroll
    for (int r = 0; r < 4; r++) {
        int row = row0 + quad * 4 + r;
        if (row >= N) continue;
#pragma unroll
        for (int t = 0; t < 4; t++) {
            float v0 = fmaxf(acc0[t][r] + b1[t * 16 + m], 0.f);
            h1h[(size_t)row * 64 + t * 16 + m] = (_Float16)v0;
            zh[(size_t)row * 64 + t * 16 + m] = (_Float16)acc1[t][r];
        }
    }
}

// ---------------- fused launch kernels ----------------

// L1: histD || histS || a15
__launch_bounds__(256)
__global__ void k_L1(const int* __restrict__ src, const int* __restrict__ dst,
                     unsigned* __restrict__ HD, unsigned* __restrict__ HS,
                     const float* __restrict__ in_feat,
                     const half8* __restrict__ W1pk, const half8* __restrict__ Wg1pk,
                     const float* __restrict__ b1,
                     _Float16* __restrict__ h1h, _Float16* __restrict__ zh, int N) {
    __shared__ unsigned cnt[RW];
    int bx = blockIdx.x;
    if (bx < HISTB) { hist_dev(bx, dst, HD, cnt); return; }
    bx -= HISTB;
    if (bx < HISTB) { hist_dev(bx, src, HS, cnt); return; }
    bx -= HISTB;
    a15_dev(bx, in_feat, W1pk, Wg1pk, b1, h1h, zh, N);
}

// L2: reduce(dst) || reduce(src) || prefix
__launch_bounds__(256)
__global__ void k_L2(const unsigned* __restrict__ HD, const unsigned* __restrict__ HS,
                     int* __restrict__ degin, float* __restrict__ din,
                     float* __restrict__ din2, float* __restrict__ dsq,
                     float* __restrict__ dout, unsigned* __restrict__ baseD) {
    int bx = blockIdx.x;
    if (bx < RB) { reduce_dev(bx, HD, degin, din, din2, dsq); return; }
    bx -= RB;
    if (bx < RB) { reduce_dev(bx, HS, nullptr, dout, nullptr, nullptr); return; }
    bx -= RB;
    prefix_dev(bx, HD, baseD);
}

// L3: scatter || a2 (h1h@W2 -> u0h = din*relu(...)) || zscale
__launch_bounds__(256)
__global__ void k_L3(const int* __restrict__ src, const int* __restrict__ dst,
                     const unsigned* __restrict__ baseD, int* __restrict__ colsPad,
                     const _Float16* __restrict__ h1h, const half8* __restrict__ W2pk,
                     const float* __restrict__ b2, _Float16* __restrict__ u0h,
                     const float* __restrict__ din,
                     half8* __restrict__ zh8, const float* __restrict__ dout, int N) {
    __shared__ unsigned cnt[RW];
    int bx = blockIdx.x;
    if (bx < HISTB) { scatter_dev(bx, src, dst, baseD, colsPad, cnt); return; }
    bx -= HISTB;
    if (bx < GB) {
        HSegs A;
        A.p[0] = h1h; A.ld[0] = 64;
        A.p[1] = nullptr; A.ld[1] = 0;
        A.p[2] = nullptr; A.ld[2] = 0;
        mg_dev<64, 64, false, false>(bx, A, W2pk, b2, 1, nullptr, u0h, din,
                                     nullptr, nullptr, nullptr, nullptr, N);
        return;
    }
    bx -= GB;
    zscale_dev(bx, zh8, dout, N);
}

// ---------------- edge-parallel pull SpMM over padded CSR: 1 wave/row ----------------

struct SpmmP {
    const half4v* xh; const half4v* fsub_h; const float* rowscale; const float* bias;
    half4v* yh0; const float* ms0; int relu;
};

__launch_bounds__(256)
__global__ void k_FS(SpmmP P0, SpmmP P1, const int* __restrict__ colsPad,
                     const int* __restrict__ deg, int N) {
    int bx = blockIdx.x;
    bool first = bx < SPB;
    SpmmP P = first ? P0 : P1;
    int row = (first ? bx : bx - SPB) * 4 + (threadIdx.x >> 6);
    if (row >= N) return;
    int lane = threadIdx.x & 63;
    int sub = lane >> 4, c = lane & 15;
    int dg = deg[row];
    int base = row * 64;
    int e = base + sub;
    int end = base + dg;
    float ax = 0.f, ay = 0.f, az = 0.f, aw = 0.f;
    for (; e + 12 < end; e += 16) {
        int s0 = colsPad[e], s1 = colsPad[e + 4], s2 = colsPad[e + 8], s3 = colsPad[e + 12];
        half4v v0 = P.xh[(size_t)s0 * 16 + c];
        half4v v1 = P.xh[(size_t)s1 * 16 + c];
        half4v v2 = P.xh[(size_t)s2 * 16 + c];
        half4v v3 = P.xh[(size_t)s3 * 16 + c];
        ax += (float)v0.x + (float)v1.x + (float)v2.x + (float)v3.x;
        ay += (float)v0.y + (float)v1.y + (float)v2.y + (float)v3.y;
        az += (float)v0.z + (float)v1.z + (float)v2.z + (float)v3.z;
        aw += (float)v0.w + (float)v1.w + (float)v2.w + (float)v3.w;
    }
    for (; e < end; e += 4) {
        int s = colsPad[e];
        half4v v = P.xh[(size_t)s * 16 + c];
        ax += (float)v.x; ay += (float)v.y; az += (float)v.z; aw += (float)v.w;
    }
    ax += __shfl_xor(ax, 16); ay += __shfl_xor(ay, 16);
    az += __shfl_xor(az, 16); aw += __shfl_xor(aw, 16);
    ax += __shfl_xor(ax, 32); ay += __shfl_xor(ay, 32);
    az += __shfl_xor(az, 32); aw += __shfl_xor(aw, 32);
    if (sub != 0) return;
    size_t oidx = (size_t)row * 16 + c;
    if (P.fsub_h) {
        float d = P.rowscale[row];
        half4v f = P.fsub_h[oidx];
        ax = (float)f.x - ax * d; ay = (float)f.y - ay * d;
        az = (float)f.z - az * d; aw = (float)f.w - aw * d;
    } else {
        if (P.rowscale) { float d = P.rowscale[row]; ax *= d; ay *= d; az *= d; aw *= d; }
        if (P.bias) {
            float4 bb = ((const float4*)P.bias)[c];
            ax += bb.x; ay += bb.y; az += bb.z; aw += bb.w;
        }
        if (P.relu) {
            ax = fmaxf(ax, 0.f); ay = fmaxf(ay, 0.f);
            az = fmaxf(az, 0.f); aw = fmaxf(aw, 0.f);
        }
    }
    float mm = P.ms0 ? P.ms0[row] : 1.f;
    half4v h;
    h.x = (_Float16)(ax * mm); h.y = (_Float16)(ay * mm);
    h.z = (_Float16)(az * mm); h.w = (_Float16)(aw * mm);
    P.yh0[oidx] = h;
}

// F3: a3 (u-space A rows scaled by sqrt(deg)) -> out  ||  a6 -> emb
__launch_bounds__(256)
__global__ void k_F3(const _Float16* __restrict__ u0h, const _Float16* __restrict__ u1h,
                     const _Float16* __restrict__ u2h, const half8* __restrict__ wcpk,
                     const float* __restrict__ b3, const float* __restrict__ dsq,
                     const float* __restrict__ W4, const float* __restrict__ b4,
                     float* __restrict__ outp,
                     const _Float16* __restrict__ sgh, const half8* __restrict__ Wg2pk,
                     const float* __restrict__ bg2, float* __restrict__ emb, int N) {
    int bx = blockIdx.x;
    if (bx < GB) {
        HSegs A;
        A.p[0] = u0h; A.ld[0] = 64;
        A.p[1] = u1h; A.ld[1] = 64;
        A.p[2] = u2h; A.ld[2] = 64;
        mg_dev<64, 192, true, true>(bx, A, wcpk, b3, 1, nullptr, nullptr, nullptr,
                                    dsq, W4, b4, outp, N);
        return;
    }
    bx -= GB;
    HSegs A;
    A.p[0] = sgh; A.ld[0] = 64;
    A.p[1] = nullptr; A.ld[1] = 0;
    A.p[2] = nullptr; A.ld[2] = 0;
    mg_dev<128, 64, false, false>(bx, A, Wg2pk, bg2, 0, emb, nullptr, nullptr,
                                  nullptr, nullptr, nullptr, nullptr, N);
}

extern "C" void kernel_launch(void* const* d_in, const int* in_sizes, int n_in,
                              void* d_out, int out_size, void* d_ws, size_t ws_size,
                              hipStream_t stream) {
    const int N = NN;
    const float* in_feat = (const float*)d_in[0];
    const int* src = (const int*)d_in[1];
    const int* dst = (const int*)d_in[2];
    const float* W1 = (const float*)d_in[3];
    const float* b1 = (const float*)d_in[4];
    const float* W2 = (const float*)d_in[5];
    const float* b2 = (const float*)d_in[6];
    const float* W3 = (const float*)d_in[7];
    const float* b3 = (const float*)d_in[8];
    const float* W4 = (const float*)d_in[9];
    const float* b4 = (const float*)d_in[10];
    const float* Wg1 = (const float*)d_in[11];
    const float* bg1 = (const float*)d_in[12];
    const float* Wg2 = (const float*)d_in[13];
    const float* bg2 = (const float*)d_in[14];

    float* out = (float*)d_out;                 // [N,2]
    float* emb = out + (size_t)N * 2;           // [N,128]

    // ---- workspace layout ----
    float* fw = (float*)d_ws;
    float* din  = fw;                      // [N]
    float* din2 = din + N;                 // [N]
    float* dsq  = din2 + N;                // [N]
    float* dout = dsq + N;                 // [N]
    int* degin  = (int*)(dout + N);        // [N]
    int* colsPad = degin + N;              // [N*64]
    unsigned* HD   = (unsigned*)(colsPad + (size_t)64 * N);  // [64*25000]
    unsigned* HS   = HD + (size_t)C64 * NW;                  // [64*25000]
    unsigned* baseD = HS + (size_t)C64 * NW;                 // [64*25000]
    _Float16* hp = (_Float16*)(baseD + (size_t)C64 * NW);
    _Float16* h1h   = hp;                   // [N*64]
    _Float16* u0h   = h1h + (size_t)64 * N; // [N*64]  din*h
    _Float16* u1h   = u0h + (size_t)64 * N; // [N*64]  din*L1
    _Float16* u2h   = u1h + (size_t)64 * N; // [N*64]  din*L2
    _Float16* zh    = u2h + (size_t)64 * N; // [N*64]  Z (later *dout)
    _Float16* g1h   = zh + (size_t)64 * N;  // [N*64]  g1*dout
    _Float16* sgh   = g1h + (size_t)64 * N; // [N*64]  SG*din
    _Float16* W1pk  = sgh + (size_t)64 * N; // 8192
    _Float16* W2pk  = W1pk + 8192;          // 4096
    _Float16* Wg1pk = W2pk + 4096;          // 8192
    _Float16* Wg2pk = Wg1pk + 8192;         // 8192
    _Float16* wcpk  = Wg2pk + 8192;         // 12288

    // L0: weight packs
    k_init<<<160, 256, 0, stream>>>(W1, W1pk, W2, W2pk, Wg1, Wg1pk, Wg2, Wg2pk, W3, wcpk);

    // L1: LDS histograms || fused a1+a5
    k_L1<<<2 * HISTB + GB, 256, 0, stream>>>(src, dst, HD, HS, in_feat,
        (const half8*)W1pk, (const half8*)Wg1pk, b1, h1h, zh, N);

    // L2: degree reduce + norms || chunk prefix
    k_L2<<<2 * RB + RB, 256, 0, stream>>>(HD, HS, degin, din, din2, dsq, dout, baseD);

    // L3: atomic-free scatter || a2 (-> u0h) || zscale
    k_L3<<<HISTB + GB + ZSB, 256, 0, stream>>>(src, dst, baseD, colsPad,
        h1h, (const half8*)W2pk, b2, u0h, din, (half8*)zh, dout, N);

    // L4: FS1: u1 = u0 - (1/deg)*spmm(u0)  ||  g1h = dout*relu(din*spmm(zh)+bg1)
    SpmmP p0, p1;
    p0 = {(const half4v*)u0h, (const half4v*)u0h, din2, nullptr, (half4v*)u1h, nullptr, 0};
    p1 = {(const half4v*)zh, nullptr, din, bg1, (half4v*)g1h, dout, 1};
    k_FS<<<2 * SPB, 256, 0, stream>>>(p0, p1, colsPad, degin, N);

    // L5: FS2: u2 = u1 - (1/deg)*spmm(u1)  ||  sgh = din*spmm(g1h)
    p0 = {(const half4v*)u1h, (const half4v*)u1h, din2, nullptr, (half4v*)u2h, nullptr, 0};
    p1 = {(const half4v*)g1h, nullptr, nullptr, nullptr, (half4v*)sgh, din, 0};
    k_FS<<<2 * SPB, 256, 0, stream>>>(p0, p1, colsPad, degin, N);

    // L6: F3: out || emb
    k_F3<<<2 * GB, 256, 0, stream>>>(u0h, u1h, u2h, (const half8*)wcpk, b3, dsq,
        W4, b4, out, sgh, (const half8*)Wg2pk, bg2, emb, N);
}

// Round 10
// 290.108 us; speedup vs baseline: 1.4954x; 1.0121x over previous
//
#include <hip/hip_runtime.h>
#include <hip/hip_bf16.h>
#include <math.h>

#define NN 50000
#define NE 800000
#define C64 64        // edge chunks
#define CE 12500      // edges per chunk (NE/C64)
#define RW 12500      // packed u32 words per node range (25000 nodes)
#define NW 25000      // total packed words (NN/2)
#define HISTB 128     // hist blocks per direction (64 chunks x 2 ranges)
#define RB 98         // cdiv(NW,256)
#define GB 782        // cdiv(NN,64)
#define ZSB 782
#define FSB 25000     // FS blocks: 3125 groups x 8 (4 P0 + 4 P1), 4 rows each

typedef _Float16 half8 __attribute__((ext_vector_type(8)));
typedef _Float16 half4v __attribute__((ext_vector_type(4)));
typedef float f32x4 __attribute__((ext_vector_type(4)));

static inline int cdiv(int a, int b) { return (a + b - 1) / b; }

// ---------------- weight packing ----------------

// B-frag pack position for MFMA 16x16x32: W[k][n] (K x M, row-major)
__device__ inline size_t pack_pos(int k, int n, int K, int M) {
    int tile = n >> 4;
    int kstep = k >> 5;
    int quad = (k >> 3) & 3;
    int j = k & 7;
    int lane = (quad << 4) | (n & 15);
    return ((size_t)(tile * (K >> 5) + kstep) * 64 + lane) * 8 + j;
}

__device__ void pack_std_dev(int bx, const float* __restrict__ W, _Float16* __restrict__ Wpk,
                             int K, int M) {
    int idx = bx * 256 + threadIdx.x;
    if (idx >= K * M) return;
    int k = idx / M, n = idx % M;
    Wpk[pack_pos(k, n, K, M)] = (_Float16)W[idx];
}

__device__ void pack_wc_dev(int bx, const float* __restrict__ W3, _Float16* __restrict__ wcpk) {
    int idx = bx * 256 + threadIdx.x;
    if (idx >= 3 * 4096) return;
    int b = idx >> 12;
    int rem = idx & 4095;
    int k = rem >> 6, n = rem & 63;
    float w0 = W3[(0 * 64 + k) * 64 + n];
    float w1 = W3[(1 * 64 + k) * 64 + n];
    float w2 = W3[(2 * 64 + k) * 64 + n];
    float w3 = W3[(3 * 64 + k) * 64 + n];
    float w4 = W3[(4 * 64 + k) * 64 + n];
    float v;
    if (b == 0)      v = 3.f * w0;
    else if (b == 1) v = -3.f * w0 + 3.f * w1 + w3;
    else             v = 0.75f * w0 - 1.5f * w1 + 0.75f * w2 + w4;
    wcpk[pack_pos(b * 64 + k, n, 192, 64)] = (_Float16)v;
}

__launch_bounds__(256)
__global__ void k_init(const float* __restrict__ W1, _Float16* __restrict__ W1pk,
                       const float* __restrict__ W2, _Float16* __restrict__ W2pk,
                       const float* __restrict__ Wg1, _Float16* __restrict__ Wg1pk,
                       const float* __restrict__ Wg2, _Float16* __restrict__ Wg2pk,
                       const float* __restrict__ W3, _Float16* __restrict__ wcpk) {
    int bx = blockIdx.x;
    if (bx < 32) { pack_std_dev(bx, W1, W1pk, 128, 64); return; }
    bx -= 32;
    if (bx < 16) { pack_std_dev(bx, W2, W2pk, 64, 64); return; }
    bx -= 16;
    if (bx < 32) { pack_std_dev(bx, Wg1, Wg1pk, 128, 64); return; }
    bx -= 32;
    if (bx < 32) { pack_std_dev(bx, Wg2, Wg2pk, 64, 128); return; }
    bx -= 32;
    pack_wc_dev(bx, W3, wcpk);
}

// ---------------- atomic-free CSR build ----------------

__device__ void hist_dev(int bx, const int* __restrict__ idx, unsigned* __restrict__ H,
                         unsigned* __restrict__ cnt) {
    int c = bx & 63, r = bx >> 6;
    int tid = threadIdx.x;
    for (int j = tid; j < RW; j += 256) cnt[j] = 0;
    __syncthreads();
    int lo = r * 25000;
    const int* p = idx + c * CE;
    for (int i = tid; i < CE; i += 256) {
        int v = p[i] - lo;
        if ((unsigned)v < 25000u)
            atomicAdd(&cnt[v >> 1], 1u << ((v & 1) * 16));
    }
    __syncthreads();
    unsigned* outp = H + (size_t)c * NW + r * RW;
    for (int j = tid; j < RW; j += 256) outp[j] = cnt[j];
}

__device__ void reduce_dev(int bx, const unsigned* __restrict__ H, int* __restrict__ dgo,
                           float* __restrict__ o_rsq, float* __restrict__ o_inv,
                           float* __restrict__ o_sq) {
    int w = bx * 256 + threadIdx.x;
    if (w >= NW) return;
    unsigned slo = 0, shi = 0;
#pragma unroll 8
    for (int c = 0; c < 64; c++) {
        unsigned h = H[(size_t)c * NW + w];
        slo += h & 0xffffu; shi += h >> 16;
    }
    if (dgo) {
        dgo[2 * w]     = slo > 64u ? 64 : (int)slo;
        dgo[2 * w + 1] = shi > 64u ? 64 : (int)shi;
    }
    float f0 = (float)(slo < 1u ? 1u : slo);
    float f1 = (float)(shi < 1u ? 1u : shi);
    o_rsq[2 * w] = rsqrtf(f0); o_rsq[2 * w + 1] = rsqrtf(f1);
    if (o_inv) { o_inv[2 * w] = 1.f / f0; o_inv[2 * w + 1] = 1.f / f1; }
    if (o_sq)  { o_sq[2 * w] = sqrtf(f0); o_sq[2 * w + 1] = sqrtf(f1); }
}

__device__ void prefix_dev(int bx, const unsigned* __restrict__ HD, unsigned* __restrict__ baseD) {
    int w = bx * 256 + threadIdx.x;
    if (w >= NW) return;
    unsigned slo = 0, shi = 0;
    for (int c = 0; c < 64; c++) {
        unsigned b0 = slo > 64u ? 64u : slo;
        unsigned b1 = shi > 64u ? 64u : shi;
        baseD[(size_t)c * NW + w] = b0 | (b1 << 16);
        unsigned h = HD[(size_t)c * NW + w];
        slo += h & 0xffffu; shi += h >> 16;
    }
}

// deterministic scatter -> u16 padded CSR, no global atomics
__device__ void scatter_dev(int bx, const int* __restrict__ src, const int* __restrict__ dst,
                            const unsigned* __restrict__ baseD,
                            unsigned short* __restrict__ colsPad,
                            unsigned* __restrict__ cnt) {
    int c = bx & 63, r = bx >> 6;
    int tid = threadIdx.x;
    for (int j = tid; j < RW; j += 256) cnt[j] = 0;
    __syncthreads();
    int lo = r * 25000;
    const int* pd = dst + c * CE;
    const int* ps = src + c * CE;
    for (int i = tid; i < CE; i += 256) {
        int v = pd[i];
        int lv = v - lo;
        if ((unsigned)lv < 25000u) {
            unsigned old = atomicAdd(&cnt[lv >> 1], 1u << ((lv & 1) * 16));
            unsigned rank = (old >> ((lv & 1) * 16)) & 0xffffu;
            unsigned base = (baseD[(size_t)c * NW + (v >> 1)] >> ((v & 1) * 16)) & 0xffffu;
            unsigned pos = base + rank;
            if (pos < 64u) colsPad[(size_t)v * 64 + pos] = (unsigned short)ps[i];
        }
    }
}

// zh *= dout (16 halves/thread)
__device__ void zscale_dev(int bx, half8* __restrict__ zh8, const float* __restrict__ dout, int N) {
    int idx = bx * 256 + threadIdx.x;
    if (idx >= N * 4) return;
    int row = idx >> 2;
    float m = dout[row];
    half8 a = zh8[idx * 2], b = zh8[idx * 2 + 1];
#pragma unroll
    for (int j = 0; j < 8; j++) {
        a[j] = (_Float16)((float)a[j] * m);
        b[j] = (_Float16)((float)b[j] * m);
    }
    zh8[idx * 2] = a; zh8[idx * 2 + 1] = b;
}

// ---------------- MFMA GEMM device functions (no LDS) ----------------

struct HSegs { const _Float16* p[3]; int ld[3]; };

template <int M, int K, bool OUTW, bool RSCA>
__device__ void mg_dev(int bx, HSegs A, const half8* __restrict__ Wpk,
                       const float* __restrict__ bias, int relu,
                       float* __restrict__ C,
                       _Float16* __restrict__ Ch0, const float* __restrict__ ms0,
                       const float* __restrict__ rsc,
                       const float* __restrict__ W4, const float* __restrict__ b4,
                       float* __restrict__ outp, int N) {
    constexpr int NT = M / 16;
    constexpr int NKS = K / 32;
    int tid = threadIdx.x;
    int wave = tid >> 6, lane = tid & 63;
    int quad = lane >> 4, m = lane & 15;
    int row0 = bx * 64 + wave * 16;
    int rowA = row0 + m; if (rowA >= N) rowA = N - 1;
    _Float16 hs = (_Float16)1.f;
    if (RSCA) hs = (_Float16)rsc[rowA];
    f32x4 acc[NT];
#pragma unroll
    for (int t = 0; t < NT; t++) acc[t] = (f32x4){0.f, 0.f, 0.f, 0.f};
#pragma unroll
    for (int ks = 0; ks < NKS; ks++) {
        const _Float16* ap = A.p[ks >> 1] + (size_t)rowA * A.ld[ks >> 1] + (ks & 1) * 32 + quad * 8;
        half8 af = *(const half8*)ap;
        if (RSCA) {
#pragma unroll
            for (int j = 0; j < 8; j++) af[j] *= hs;
        }
#pragma unroll
        for (int t = 0; t < NT; t++) {
            half8 bf = Wpk[(t * NKS + ks) * 64 + lane];
            acc[t] = __builtin_amdgcn_mfma_f32_16x16x32_f16(af, bf, acc[t], 0, 0, 0);
        }
    }
    float outv[NT][4];
#pragma unroll
    for (int t = 0; t < NT; t++) {
        float bv = bias ? bias[t * 16 + m] : 0.f;
#pragma unroll
        for (int r = 0; r < 4; r++) {
            float v = acc[t][r] + bv;
            if (relu) v = fmaxf(v, 0.f);
            outv[t][r] = v;
        }
    }
    if (OUTW) {
        float w40[NT], w41[NT];
#pragma unroll
        for (int t = 0; t < NT; t++) {
            w40[t] = W4[(t * 16 + m) * 2];
            w41[t] = W4[(t * 16 + m) * 2 + 1];
        }
#pragma unroll
        for (int r = 0; r < 4; r++) {
            float p0 = 0.f, p1 = 0.f;
#pragma unroll
            for (int t = 0; t < NT; t++) {
                p0 += outv[t][r] * w40[t];
                p1 += outv[t][r] * w41[t];
            }
#pragma unroll
            for (int off = 1; off < 16; off <<= 1) {
                p0 += __shfl_xor(p0, off);
                p1 += __shfl_xor(p1, off);
            }
            int row = row0 + quad * 4 + r;
            if (m == 0 && row < N) {
                outp[(size_t)row * 2 + 0] = p0 + b4[0];
                outp[(size_t)row * 2 + 1] = p1 + b4[1];
            }
        }
    }
    if (C || Ch0) {
#pragma unroll
        for (int r = 0; r < 4; r++) {
            int row = row0 + quad * 4 + r;
            if (row >= N) continue;
            float m0 = (Ch0 && ms0) ? ms0[row] : 1.f;
#pragma unroll
            for (int t = 0; t < NT; t++) {
                size_t off = (size_t)row * M + t * 16 + m;
                if (C)   C[off] = outv[t][r];
                if (Ch0) Ch0[off] = (_Float16)(outv[t][r] * m0);
            }
        }
    }
}

// fused a1+a5: shared A-fragments (f32 in_feat -> fp16), two B matrices
__device__ void a15_dev(int bx, const float* __restrict__ in_feat,
                        const half8* __restrict__ W1pk, const half8* __restrict__ Wg1pk,
                        const float* __restrict__ b1,
                        _Float16* __restrict__ h1h, _Float16* __restrict__ zh, int N) {
    int tid = threadIdx.x;
    int wave = tid >> 6, lane = tid & 63;
    int quad = lane >> 4, m = lane & 15;
    int row0 = bx * 64 + wave * 16;
    int rowA = row0 + m; if (rowA >= N) rowA = N - 1;
    f32x4 acc0[4], acc1[4];
#pragma unroll
    for (int t = 0; t < 4; t++) {
        acc0[t] = (f32x4){0.f, 0.f, 0.f, 0.f};
        acc1[t] = (f32x4){0.f, 0.f, 0.f, 0.f};
    }
#pragma unroll
    for (int ks = 0; ks < 4; ks++) {
        const float* ap = in_feat + (size_t)rowA * 128 + ks * 32 + quad * 8;
        float4 u = *(const float4*)ap;
        float4 v = *(const float4*)(ap + 4);
        half8 af;
        af[0] = (_Float16)u.x; af[1] = (_Float16)u.y; af[2] = (_Float16)u.z; af[3] = (_Float16)u.w;
        af[4] = (_Float16)v.x; af[5] = (_Float16)v.y; af[6] = (_Float16)v.z; af[7] = (_Float16)v.w;
#pragma unroll
        for (int t = 0; t < 4; t++) {
            acc0[t] = __builtin_amdgcn_mfma_f32_16x16x32_f16(af, W1pk[(t * 4 + ks) * 64 + lane], acc0[t], 0, 0, 0);
            acc1[t] = __builtin_amdgcn_mfma_f32_16x16x32_f16(af, Wg1pk[(t * 4 + ks) * 64 + lane], acc1[t], 0, 0, 0);
        }
    }
#pragma unroll
    for (int r = 0; r < 4; r++) {
        int row = row0 + quad * 4 + r;
        if (row >= N) continue;
#pragma unroll
        for (int t = 0; t < 4; t++) {
            float v0 = fmaxf(acc0[t][r] + b1[t * 16 + m], 0.f);
            h1h[(size_t)row * 64 + t * 16 + m] = (_Float16)v0;
            zh[(size_t)row * 64 + t * 16 + m] = (_Float16)acc1[t][r];
        }
    }
}

// ---------------- fused launch kernels ----------------

// L1: histD || histS || a15
__launch_bounds__(256)
__global__ void k_L1(const int* __restrict__ src, const int* __restrict__ dst,
                     unsigned* __restrict__ HD, unsigned* __restrict__ HS,
                     const float* __restrict__ in_feat,
                     const half8* __restrict__ W1pk, const half8* __restrict__ Wg1pk,
                     const float* __restrict__ b1,
                     _Float16* __restrict__ h1h, _Float16* __restrict__ zh, int N) {
    __shared__ unsigned cnt[RW];
    int bx = blockIdx.x;
    if (bx < HISTB) { hist_dev(bx, dst, HD, cnt); return; }
    bx -= HISTB;
    if (bx < HISTB) { hist_dev(bx, src, HS, cnt); return; }
    bx -= HISTB;
    a15_dev(bx, in_feat, W1pk, Wg1pk, b1, h1h, zh, N);
}

// L2: reduce(dst) || reduce(src) || prefix
__launch_bounds__(256)
__global__ void k_L2(const unsigned* __restrict__ HD, const unsigned* __restrict__ HS,
                     int* __restrict__ degin, float* __restrict__ din,
                     float* __restrict__ din2, float* __restrict__ dsq,
                     float* __restrict__ dout, unsigned* __restrict__ baseD) {
    int bx = blockIdx.x;
    if (bx < RB) { reduce_dev(bx, HD, degin, din, din2, dsq); return; }
    bx -= RB;
    if (bx < RB) { reduce_dev(bx, HS, nullptr, dout, nullptr, nullptr); return; }
    bx -= RB;
    prefix_dev(bx, HD, baseD);
}

// L3: scatter || a2 (h1h@W2 -> u0h = din*relu(...)) || zscale
__launch_bounds__(256)
__global__ void k_L3(const int* __restrict__ src, const int* __restrict__ dst,
                     const unsigned* __restrict__ baseD, unsigned short* __restrict__ colsPad,
                     const _Float16* __restrict__ h1h, const half8* __restrict__ W2pk,
                     const float* __restrict__ b2, _Float16* __restrict__ u0h,
                     const float* __restrict__ din,
                     half8* __restrict__ zh8, const float* __restrict__ dout, int N) {
    __shared__ unsigned cnt[RW];
    int bx = blockIdx.x;
    if (bx < HISTB) { scatter_dev(bx, src, dst, baseD, colsPad, cnt); return; }
    bx -= HISTB;
    if (bx < GB) {
        HSegs A;
        A.p[0] = h1h; A.ld[0] = 64;
        A.p[1] = nullptr; A.ld[1] = 0;
        A.p[2] = nullptr; A.ld[2] = 0;
        mg_dev<64, 64, false, false>(bx, A, W2pk, b2, 1, nullptr, u0h, din,
                                     nullptr, nullptr, nullptr, nullptr, N);
        return;
    }
    bx -= GB;
    zscale_dev(bx, zh8, dout, N);
}

// ---------------- edge-parallel pull SpMM, XCD-partitioned by table ----------------

struct SpmmP {
    const half4v* xh; const half4v* fsub_h; const float* rowscale; const float* bias;
    half4v* yh0; const float* ms0; int relu;
};

// blocks: 3125 groups x 8; within a group, bx&7 in {0..3} -> P0, {4..7} -> P1.
// With round-robin block->XCD assignment this pins each table to 4 XCDs,
// halving compulsory cross-XCD L2 fills of the 6.4 MB gather tables.
__launch_bounds__(256)
__global__ void k_FS(SpmmP P0, SpmmP P1, const unsigned short* __restrict__ colsPad,
                     const int* __restrict__ deg, int N) {
    int bx = blockIdx.x;
    int g = bx >> 3, x = bx & 7;
    bool first = x < 4;
    SpmmP P = first ? P0 : P1;
    int row = g * 16 + (x & 3) * 4 + (threadIdx.x >> 6);
    if (row >= N) return;
    int lane = threadIdx.x & 63;
    int sub = lane >> 4, c = lane & 15;
    int dg = deg[row];
    int base = row * 64;
    int e = base + sub;
    int end = base + dg;
    float ax = 0.f, ay = 0.f, az = 0.f, aw = 0.f;
    for (; e + 12 < end; e += 16) {
        int s0 = colsPad[e], s1 = colsPad[e + 4], s2 = colsPad[e + 8], s3 = colsPad[e + 12];
        half4v v0 = P.xh[(size_t)s0 * 16 + c];
        half4v v1 = P.xh[(size_t)s1 * 16 + c];
        half4v v2 = P.xh[(size_t)s2 * 16 + c];
        half4v v3 = P.xh[(size_t)s3 * 16 + c];
        ax += (float)v0.x + (float)v1.x + (float)v2.x + (float)v3.x;
        ay += (float)v0.y + (float)v1.y + (float)v2.y + (float)v3.y;
        az += (float)v0.z + (float)v1.z + (float)v2.z + (float)v3.z;
        aw += (float)v0.w + (float)v1.w + (float)v2.w + (float)v3.w;
    }
    for (; e < end; e += 4) {
        int s = colsPad[e];
        half4v v = P.xh[(size_t)s * 16 + c];
        ax += (float)v.x; ay += (float)v.y; az += (float)v.z; aw += (float)v.w;
    }
    ax += __shfl_xor(ax, 16); ay += __shfl_xor(ay, 16);
    az += __shfl_xor(az, 16); aw += __shfl_xor(aw, 16);
    ax += __shfl_xor(ax, 32); ay += __shfl_xor(ay, 32);
    az += __shfl_xor(az, 32); aw += __shfl_xor(aw, 32);
    if (sub != 0) return;
    size_t oidx = (size_t)row * 16 + c;
    if (P.fsub_h) {
        float d = P.rowscale[row];
        half4v f = P.fsub_h[oidx];
        ax = (float)f.x - ax * d; ay = (float)f.y - ay * d;
        az = (float)f.z - az * d; aw = (float)f.w - aw * d;
    } else {
        if (P.rowscale) { float d = P.rowscale[row]; ax *= d; ay *= d; az *= d; aw *= d; }
        if (P.bias) {
            float4 bb = ((const float4*)P.bias)[c];
            ax += bb.x; ay += bb.y; az += bb.z; aw += bb.w;
        }
        if (P.relu) {
            ax = fmaxf(ax, 0.f); ay = fmaxf(ay, 0.f);
            az = fmaxf(az, 0.f); aw = fmaxf(aw, 0.f);
        }
    }
    float mm = P.ms0 ? P.ms0[row] : 1.f;
    half4v h;
    h.x = (_Float16)(ax * mm); h.y = (_Float16)(ay * mm);
    h.z = (_Float16)(az * mm); h.w = (_Float16)(aw * mm);
    P.yh0[oidx] = h;
}

// F3: a3 (u-space, rows scaled by sqrt(deg)) -> out || a6 -> emb
__launch_bounds__(256)
__global__ void k_F3(const _Float16* __restrict__ u0h, const _Float16* __restrict__ u1h,
                     const _Float16* __restrict__ u2h, const half8* __restrict__ wcpk,
                     const float* __restrict__ b3, const float* __restrict__ dsq,
                     const float* __restrict__ W4, const float* __restrict__ b4,
                     float* __restrict__ outp,
                     const _Float16* __restrict__ sgh, const half8* __restrict__ Wg2pk,
                     const float* __restrict__ bg2, float* __restrict__ emb, int N) {
    int bx = blockIdx.x;
    if (bx < GB) {
        HSegs A;
        A.p[0] = u0h; A.ld[0] = 64;
        A.p[1] = u1h; A.ld[1] = 64;
        A.p[2] = u2h; A.ld[2] = 64;
        mg_dev<64, 192, true, true>(bx, A, wcpk, b3, 1, nullptr, nullptr, nullptr,
                                    dsq, W4, b4, outp, N);
        return;
    }
    bx -= GB;
    HSegs A;
    A.p[0] = sgh; A.ld[0] = 64;
    A.p[1] = nullptr; A.ld[1] = 0;
    A.p[2] = nullptr; A.ld[2] = 0;
    mg_dev<128, 64, false, false>(bx, A, Wg2pk, bg2, 0, emb, nullptr, nullptr,
                                  nullptr, nullptr, nullptr, nullptr, N);
}

extern "C" void kernel_launch(void* const* d_in, const int* in_sizes, int n_in,
                              void* d_out, int out_size, void* d_ws, size_t ws_size,
                              hipStream_t stream) {
    const int N = NN;
    const float* in_feat = (const float*)d_in[0];
    const int* src = (const int*)d_in[1];
    const int* dst = (const int*)d_in[2];
    const float* W1 = (const float*)d_in[3];
    const float* b1 = (const float*)d_in[4];
    const float* W2 = (const float*)d_in[5];
    const float* b2 = (const float*)d_in[6];
    const float* W3 = (const float*)d_in[7];
    const float* b3 = (const float*)d_in[8];
    const float* W4 = (const float*)d_in[9];
    const float* b4 = (const float*)d_in[10];
    const float* Wg1 = (const float*)d_in[11];
    const float* bg1 = (const float*)d_in[12];
    const float* Wg2 = (const float*)d_in[13];
    const float* bg2 = (const float*)d_in[14];

    float* out = (float*)d_out;                 // [N,2]
    float* emb = out + (size_t)N * 2;           // [N,128]

    // ---- workspace layout ----
    float* fw = (float*)d_ws;
    float* din  = fw;                      // [N]
    float* din2 = din + N;                 // [N]
    float* dsq  = din2 + N;                // [N]
    float* dout = dsq + N;                 // [N]
    int* degin  = (int*)(dout + N);        // [N]
    unsigned short* colsPad = (unsigned short*)(degin + N);   // [N*64] u16
    unsigned* HD   = (unsigned*)(colsPad + (size_t)64 * N);   // [64*25000]
    unsigned* HS   = HD + (size_t)C64 * NW;                   // [64*25000]
    unsigned* baseD = HS + (size_t)C64 * NW;                  // [64*25000]
    _Float16* hp = (_Float16*)(baseD + (size_t)C64 * NW);
    _Float16* h1h   = hp;                   // [N*64]
    _Float16* u0h   = h1h + (size_t)64 * N; // [N*64]  din*h
    _Float16* u1h   = u0h + (size_t)64 * N; // [N*64]  din*L1
    _Float16* u2h   = u1h + (size_t)64 * N; // [N*64]  din*L2
    _Float16* zh    = u2h + (size_t)64 * N; // [N*64]  Z (later *dout)
    _Float16* g1h   = zh + (size_t)64 * N;  // [N*64]  g1*dout
    _Float16* sgh   = g1h + (size_t)64 * N; // [N*64]  SG*din
    _Float16* W1pk  = sgh + (size_t)64 * N; // 8192
    _Float16* W2pk  = W1pk + 8192;          // 4096
    _Float16* Wg1pk = W2pk + 4096;          // 8192
    _Float16* Wg2pk = Wg1pk + 8192;         // 8192
    _Float16* wcpk  = Wg2pk + 8192;         // 12288

    // L0: weight packs
    k_init<<<160, 256, 0, stream>>>(W1, W1pk, W2, W2pk, Wg1, Wg1pk, Wg2, Wg2pk, W3, wcpk);

    // L1: LDS histograms || fused a1+a5
    k_L1<<<2 * HISTB + GB, 256, 0, stream>>>(src, dst, HD, HS, in_feat,
        (const half8*)W1pk, (const half8*)Wg1pk, b1, h1h, zh, N);

    // L2: degree reduce + norms || chunk prefix
    k_L2<<<2 * RB + RB, 256, 0, stream>>>(HD, HS, degin, din, din2, dsq, dout, baseD);

    // L3: atomic-free scatter || a2 (-> u0h) || zscale
    k_L3<<<HISTB + GB + ZSB, 256, 0, stream>>>(src, dst, baseD, colsPad,
        h1h, (const half8*)W2pk, b2, u0h, din, (half8*)zh, dout, N);

    // L4: FS1: u1 = u0 - (1/deg)*spmm(u0)  ||  g1h = dout*relu(din*spmm(zh)+bg1)
    SpmmP p0, p1;
    p0 = {(const half4v*)u0h, (const half4v*)u0h, din2, nullptr, (half4v*)u1h, nullptr, 0};
    p1 = {(const half4v*)zh, nullptr, din, bg1, (half4v*)g1h, dout, 1};
    k_FS<<<FSB, 256, 0, stream>>>(p0, p1, colsPad, degin, N);

    // L5: FS2: u2 = u1 - (1/deg)*spmm(u1)  ||  sgh = din*spmm(g1h)
    p0 = {(const half4v*)u1h, (const half4v*)u1h, din2, nullptr, (half4v*)u2h, nullptr, 0};
    p1 = {(const half4v*)g1h, nullptr, nullptr, nullptr, (half4v*)sgh, din, 0};
    k_FS<<<FSB, 256, 0, stream>>>(p0, p1, colsPad, degin, N);

    // L6: F3: out || emb
    k_F3<<<2 * GB, 256, 0, stream>>>(u0h, u1h, u2h, (const half8*)wcpk, b3, dsq,
        W4, b4, out, sgh, (const half8*)Wg2pk, bg2, emb, N);
}

// Round 11
// 266.194 us; speedup vs baseline: 1.6298x; 1.0898x over previous
//
#include <hip/hip_runtime.h>
#include <hip/hip_bf16.h>
#include <math.h>

#define NN 50000
#define NE 800000
#define C64 64        // edge chunks
#define CE 12500      // edges per chunk (NE/C64)
#define RW 12500      // packed u32 words per node range (25000 nodes)
#define NW 25000      // total packed words (NN/2)
#define HISTB 128     // hist blocks per direction (64 chunks x 2 ranges)
#define RB 98         // cdiv(NW,256)
#define GB 782        // cdiv(NN,64)
#define ZSB 782
#define FSG 3125      // FS groups: 16 rows per block
#define FSB 6250      // FS blocks: FSG x 2 (P0 | P1)

typedef _Float16 half8 __attribute__((ext_vector_type(8)));
typedef _Float16 half4v __attribute__((ext_vector_type(4)));
typedef float f32x4 __attribute__((ext_vector_type(4)));

static inline int cdiv(int a, int b) { return (a + b - 1) / b; }

// ---------------- weight packing ----------------

// B-frag pack position for MFMA 16x16x32: W[k][n] (K x M, row-major)
__device__ inline size_t pack_pos(int k, int n, int K, int M) {
    int tile = n >> 4;
    int kstep = k >> 5;
    int quad = (k >> 3) & 3;
    int j = k & 7;
    int lane = (quad << 4) | (n & 15);
    return ((size_t)(tile * (K >> 5) + kstep) * 64 + lane) * 8 + j;
}

__device__ void pack_std_dev(int bx, const float* __restrict__ W, _Float16* __restrict__ Wpk,
                             int K, int M) {
    int idx = bx * 256 + threadIdx.x;
    if (idx >= K * M) return;
    int k = idx / M, n = idx % M;
    Wpk[pack_pos(k, n, K, M)] = (_Float16)W[idx];
}

__device__ void pack_wc_dev(int bx, const float* __restrict__ W3, _Float16* __restrict__ wcpk) {
    int idx = bx * 256 + threadIdx.x;
    if (idx >= 3 * 4096) return;
    int b = idx >> 12;
    int rem = idx & 4095;
    int k = rem >> 6, n = rem & 63;
    float w0 = W3[(0 * 64 + k) * 64 + n];
    float w1 = W3[(1 * 64 + k) * 64 + n];
    float w2 = W3[(2 * 64 + k) * 64 + n];
    float w3 = W3[(3 * 64 + k) * 64 + n];
    float w4 = W3[(4 * 64 + k) * 64 + n];
    float v;
    if (b == 0)      v = 3.f * w0;
    else if (b == 1) v = -3.f * w0 + 3.f * w1 + w3;
    else             v = 0.75f * w0 - 1.5f * w1 + 0.75f * w2 + w4;
    wcpk[pack_pos(b * 64 + k, n, 192, 64)] = (_Float16)v;
}

__launch_bounds__(256)
__global__ void k_init(const float* __restrict__ W1, _Float16* __restrict__ W1pk,
                       const float* __restrict__ W2, _Float16* __restrict__ W2pk,
                       const float* __restrict__ Wg1, _Float16* __restrict__ Wg1pk,
                       const float* __restrict__ Wg2, _Float16* __restrict__ Wg2pk,
                       const float* __restrict__ W3, _Float16* __restrict__ wcpk) {
    int bx = blockIdx.x;
    if (bx < 32) { pack_std_dev(bx, W1, W1pk, 128, 64); return; }
    bx -= 32;
    if (bx < 16) { pack_std_dev(bx, W2, W2pk, 64, 64); return; }
    bx -= 16;
    if (bx < 32) { pack_std_dev(bx, Wg1, Wg1pk, 128, 64); return; }
    bx -= 32;
    if (bx < 32) { pack_std_dev(bx, Wg2, Wg2pk, 64, 128); return; }
    bx -= 32;
    pack_wc_dev(bx, W3, wcpk);
}

// ---------------- atomic-free CSR build ----------------

__device__ void hist_dev(int bx, const int* __restrict__ idx, unsigned* __restrict__ H,
                         unsigned* __restrict__ cnt) {
    int c = bx & 63, r = bx >> 6;
    int tid = threadIdx.x;
    for (int j = tid; j < RW; j += 256) cnt[j] = 0;
    __syncthreads();
    int lo = r * 25000;
    const int* p = idx + c * CE;
    for (int i = tid; i < CE; i += 256) {
        int v = p[i] - lo;
        if ((unsigned)v < 25000u)
            atomicAdd(&cnt[v >> 1], 1u << ((v & 1) * 16));
    }
    __syncthreads();
    unsigned* outp = H + (size_t)c * NW + r * RW;
    for (int j = tid; j < RW; j += 256) outp[j] = cnt[j];
}

__device__ void reduce_dev(int bx, const unsigned* __restrict__ H, int* __restrict__ dgo,
                           float* __restrict__ o_rsq, float* __restrict__ o_inv,
                           float* __restrict__ o_sq) {
    int w = bx * 256 + threadIdx.x;
    if (w >= NW) return;
    unsigned slo = 0, shi = 0;
#pragma unroll 8
    for (int c = 0; c < 64; c++) {
        unsigned h = H[(size_t)c * NW + w];
        slo += h & 0xffffu; shi += h >> 16;
    }
    if (dgo) {
        dgo[2 * w]     = slo > 64u ? 64 : (int)slo;
        dgo[2 * w + 1] = shi > 64u ? 64 : (int)shi;
    }
    float f0 = (float)(slo < 1u ? 1u : slo);
    float f1 = (float)(shi < 1u ? 1u : shi);
    o_rsq[2 * w] = rsqrtf(f0); o_rsq[2 * w + 1] = rsqrtf(f1);
    if (o_inv) { o_inv[2 * w] = 1.f / f0; o_inv[2 * w + 1] = 1.f / f1; }
    if (o_sq)  { o_sq[2 * w] = sqrtf(f0); o_sq[2 * w + 1] = sqrtf(f1); }
}

__device__ void prefix_dev(int bx, const unsigned* __restrict__ HD, unsigned* __restrict__ baseD) {
    int w = bx * 256 + threadIdx.x;
    if (w >= NW) return;
    unsigned slo = 0, shi = 0;
    for (int c = 0; c < 64; c++) {
        unsigned b0 = slo > 64u ? 64u : slo;
        unsigned b1 = shi > 64u ? 64u : shi;
        baseD[(size_t)c * NW + w] = b0 | (b1 << 16);
        unsigned h = HD[(size_t)c * NW + w];
        slo += h & 0xffffu; shi += h >> 16;
    }
}

// deterministic scatter -> u16 padded CSR, no global atomics
__device__ void scatter_dev(int bx, const int* __restrict__ src, const int* __restrict__ dst,
                            const unsigned* __restrict__ baseD,
                            unsigned short* __restrict__ colsPad,
                            unsigned* __restrict__ cnt) {
    int c = bx & 63, r = bx >> 6;
    int tid = threadIdx.x;
    for (int j = tid; j < RW; j += 256) cnt[j] = 0;
    __syncthreads();
    int lo = r * 25000;
    const int* pd = dst + c * CE;
    const int* ps = src + c * CE;
    for (int i = tid; i < CE; i += 256) {
        int v = pd[i];
        int lv = v - lo;
        if ((unsigned)lv < 25000u) {
            unsigned old = atomicAdd(&cnt[lv >> 1], 1u << ((lv & 1) * 16));
            unsigned rank = (old >> ((lv & 1) * 16)) & 0xffffu;
            unsigned base = (baseD[(size_t)c * NW + (v >> 1)] >> ((v & 1) * 16)) & 0xffffu;
            unsigned pos = base + rank;
            if (pos < 64u) colsPad[(size_t)v * 64 + pos] = (unsigned short)ps[i];
        }
    }
}

// zh *= dout (16 halves/thread)
__device__ void zscale_dev(int bx, half8* __restrict__ zh8, const float* __restrict__ dout, int N) {
    int idx = bx * 256 + threadIdx.x;
    if (idx >= N * 4) return;
    int row = idx >> 2;
    float m = dout[row];
    half8 a = zh8[idx * 2], b = zh8[idx * 2 + 1];
#pragma unroll
    for (int j = 0; j < 8; j++) {
        a[j] = (_Float16)((float)a[j] * m);
        b[j] = (_Float16)((float)b[j] * m);
    }
    zh8[idx * 2] = a; zh8[idx * 2 + 1] = b;
}

// ---------------- MFMA GEMM device functions (no LDS) ----------------

struct HSegs { const _Float16* p[3]; int ld[3]; };

template <int M, int K, bool OUTW, bool RSCA>
__device__ void mg_dev(int bx, HSegs A, const half8* __restrict__ Wpk,
                       const float* __restrict__ bias, int relu,
                       float* __restrict__ C,
                       _Float16* __restrict__ Ch0, const float* __restrict__ ms0,
                       const float* __restrict__ rsc,
                       const float* __restrict__ W4, const float* __restrict__ b4,
                       float* __restrict__ outp, int N) {
    constexpr int NT = M / 16;
    constexpr int NKS = K / 32;
    int tid = threadIdx.x;
    int wave = tid >> 6, lane = tid & 63;
    int quad = lane >> 4, m = lane & 15;
    int row0 = bx * 64 + wave * 16;
    int rowA = row0 + m; if (rowA >= N) rowA = N - 1;
    _Float16 hs = (_Float16)1.f;
    if (RSCA) hs = (_Float16)rsc[rowA];
    f32x4 acc[NT];
#pragma unroll
    for (int t = 0; t < NT; t++) acc[t] = (f32x4){0.f, 0.f, 0.f, 0.f};
#pragma unroll
    for (int ks = 0; ks < NKS; ks++) {
        const _Float16* ap = A.p[ks >> 1] + (size_t)rowA * A.ld[ks >> 1] + (ks & 1) * 32 + quad * 8;
        half8 af = *(const half8*)ap;
        if (RSCA) {
#pragma unroll
            for (int j = 0; j < 8; j++) af[j] *= hs;
        }
#pragma unroll
        for (int t = 0; t < NT; t++) {
            half8 bf = Wpk[(t * NKS + ks) * 64 + lane];
            acc[t] = __builtin_amdgcn_mfma_f32_16x16x32_f16(af, bf, acc[t], 0, 0, 0);
        }
    }
    float outv[NT][4];
#pragma unroll
    for (int t = 0; t < NT; t++) {
        float bv = bias ? bias[t * 16 + m] : 0.f;
#pragma unroll
        for (int r = 0; r < 4; r++) {
            float v = acc[t][r] + bv;
            if (relu) v = fmaxf(v, 0.f);
            outv[t][r] = v;
        }
    }
    if (OUTW) {
        float w40[NT], w41[NT];
#pragma unroll
        for (int t = 0; t < NT; t++) {
            w40[t] = W4[(t * 16 + m) * 2];
            w41[t] = W4[(t * 16 + m) * 2 + 1];
        }
#pragma unroll
        for (int r = 0; r < 4; r++) {
            float p0 = 0.f, p1 = 0.f;
#pragma unroll
            for (int t = 0; t < NT; t++) {
                p0 += outv[t][r] * w40[t];
                p1 += outv[t][r] * w41[t];
            }
#pragma unroll
            for (int off = 1; off < 16; off <<= 1) {
                p0 += __shfl_xor(p0, off);
                p1 += __shfl_xor(p1, off);
            }
            int row = row0 + quad * 4 + r;
            if (m == 0 && row < N) {
                outp[(size_t)row * 2 + 0] = p0 + b4[0];
                outp[(size_t)row * 2 + 1] = p1 + b4[1];
            }
        }
    }
    if (C || Ch0) {
#pragma unroll
        for (int r = 0; r < 4; r++) {
            int row = row0 + quad * 4 + r;
            if (row >= N) continue;
            float m0 = (Ch0 && ms0) ? ms0[row] : 1.f;
#pragma unroll
            for (int t = 0; t < NT; t++) {
                size_t off = (size_t)row * M + t * 16 + m;
                if (C)   C[off] = outv[t][r];
                if (Ch0) Ch0[off] = (_Float16)(outv[t][r] * m0);
            }
        }
    }
}

// fused a1+a5: shared A-fragments (f32 in_feat -> fp16), two B matrices
__device__ void a15_dev(int bx, const float* __restrict__ in_feat,
                        const half8* __restrict__ W1pk, const half8* __restrict__ Wg1pk,
                        const float* __restrict__ b1,
                        _Float16* __restrict__ h1h, _Float16* __restrict__ zh, int N) {
    int tid = threadIdx.x;
    int wave = tid >> 6, lane = tid & 63;
    int quad = lane >> 4, m = lane & 15;
    int row0 = bx * 64 + wave * 16;
    int rowA = row0 + m; if (rowA >= N) rowA = N - 1;
    f32x4 acc0[4], acc1[4];
#pragma unroll
    for (int t = 0; t < 4; t++) {
        acc0[t] = (f32x4){0.f, 0.f, 0.f, 0.f};
        acc1[t] = (f32x4){0.f, 0.f, 0.f, 0.f};
    }
#pragma unroll
    for (int ks = 0; ks < 4; ks++) {
        const float* ap = in_feat + (size_t)rowA * 128 + ks * 32 + quad * 8;
        float4 u = *(const float4*)ap;
        float4 v = *(const float4*)(ap + 4);
        half8 af;
        af[0] = (_Float16)u.x; af[1] = (_Float16)u.y; af[2] = (_Float16)u.z; af[3] = (_Float16)u.w;
        af[4] = (_Float16)v.x; af[5] = (_Float16)v.y; af[6] = (_Float16)v.z; af[7] = (_Float16)v.w;
#pragma unroll
        for (int t = 0; t < 4; t++) {
            acc0[t] = __builtin_amdgcn_mfma_f32_16x16x32_f16(af, W1pk[(t * 4 + ks) * 64 + lane], acc0[t], 0, 0, 0);
            acc1[t] = __builtin_amdgcn_mfma_f32_16x16x32_f16(af, Wg1pk[(t * 4 + ks) * 64 + lane], acc1[t], 0, 0, 0);
        }
    }
#pragma unroll
    for (int r = 0; r < 4; r++) {
        int row = row0 + quad * 4 + r;
        if (row >= N) continue;
#pragma unroll
        for (int t = 0; t < 4; t++) {
            float v0 = fmaxf(acc0[t][r] + b1[t * 16 + m], 0.f);
            h1h[(size_t)row * 64 + t * 16 + m] = (_Float16)v0;
            zh[(size_t)row * 64 + t * 16 + m] = (_Float16)acc1[t][r];
        }
    }
}

// ---------------- fused launch kernels ----------------

// L1: histD || histS || a15
__launch_bounds__(256)
__global__ void k_L1(const int* __restrict__ src, const int* __restrict__ dst,
                     unsigned* __restrict__ HD, unsigned* __restrict__ HS,
                     const float* __restrict__ in_feat,
                     const half8* __restrict__ W1pk, const half8* __restrict__ Wg1pk,
                     const float* __restrict__ b1,
                     _Float16* __restrict__ h1h, _Float16* __restrict__ zh, int N) {
    __shared__ unsigned cnt[RW];
    int bx = blockIdx.x;
    if (bx < HISTB) { hist_dev(bx, dst, HD, cnt); return; }
    bx -= HISTB;
    if (bx < HISTB) { hist_dev(bx, src, HS, cnt); return; }
    bx -= HISTB;
    a15_dev(bx, in_feat, W1pk, Wg1pk, b1, h1h, zh, N);
}

// L2: reduce(dst) || reduce(src) || prefix
__launch_bounds__(256)
__global__ void k_L2(const unsigned* __restrict__ HD, const unsigned* __restrict__ HS,
                     int* __restrict__ degin, float* __restrict__ din,
                     float* __restrict__ din2, float* __restrict__ dsq,
                     float* __restrict__ dout, unsigned* __restrict__ baseD) {
    int bx = blockIdx.x;
    if (bx < RB) { reduce_dev(bx, HD, degin, din, din2, dsq); return; }
    bx -= RB;
    if (bx < RB) { reduce_dev(bx, HS, nullptr, dout, nullptr, nullptr); return; }
    bx -= RB;
    prefix_dev(bx, HD, baseD);
}

// L3: scatter || a2 (h1h@W2 -> u0h = din*relu(...)) || zscale
__launch_bounds__(256)
__global__ void k_L3(const int* __restrict__ src, const int* __restrict__ dst,
                     const unsigned* __restrict__ baseD, unsigned short* __restrict__ colsPad,
                     const _Float16* __restrict__ h1h, const half8* __restrict__ W2pk,
                     const float* __restrict__ b2, _Float16* __restrict__ u0h,
                     const float* __restrict__ din,
                     half8* __restrict__ zh8, const float* __restrict__ dout, int N) {
    __shared__ unsigned cnt[RW];
    int bx = blockIdx.x;
    if (bx < HISTB) { scatter_dev(bx, src, dst, baseD, colsPad, cnt); return; }
    bx -= HISTB;
    if (bx < GB) {
        HSegs A;
        A.p[0] = h1h; A.ld[0] = 64;
        A.p[1] = nullptr; A.ld[1] = 0;
        A.p[2] = nullptr; A.ld[2] = 0;
        mg_dev<64, 64, false, false>(bx, A, W2pk, b2, 1, nullptr, u0h, din,
                                     nullptr, nullptr, nullptr, nullptr, N);
        return;
    }
    bx -= GB;
    zscale_dev(bx, zh8, dout, N);
}

// ---------------- edge-parallel pull SpMM: one quad (16 lanes) per row ----------------
// 4 independent rows per wave, 16 rows per block -> 16 independent load chains/wave,
// no cross-lane reduction (quad covers the full 64-dim row).

struct SpmmP {
    const half4v* xh; const half4v* fsub_h; const float* rowscale; const float* bias;
    half4v* yh0; const float* ms0; int relu;
};

typedef unsigned short ushort4v __attribute__((ext_vector_type(4)));

__launch_bounds__(256)
__global__ void k_FS(SpmmP P0, SpmmP P1, const unsigned short* __restrict__ colsPad,
                     const int* __restrict__ deg, int N) {
    int bx = blockIdx.x;
    bool first = bx < FSG;
    SpmmP P = first ? P0 : P1;
    int g = first ? bx : bx - FSG;
    int tid = threadIdx.x;
    int wave = tid >> 6, lane = tid & 63;
    int quad = lane >> 4, c = lane & 15;
    int row = g * 16 + wave * 4 + quad;
    if (row >= N) return;
    int dg = deg[row];
    const unsigned short* cp = colsPad + (size_t)row * 64;
    float ax = 0.f, ay = 0.f, az = 0.f, aw = 0.f;
    int e = 0;
    for (; e + 3 < dg; e += 4) {
        ushort4v ss = *(const ushort4v*)(cp + e);
        half4v v0 = P.xh[(size_t)ss.x * 16 + c];
        half4v v1 = P.xh[(size_t)ss.y * 16 + c];
        half4v v2 = P.xh[(size_t)ss.z * 16 + c];
        half4v v3 = P.xh[(size_t)ss.w * 16 + c];
        ax += (float)v0.x + (float)v1.x + (float)v2.x + (float)v3.x;
        ay += (float)v0.y + (float)v1.y + (float)v2.y + (float)v3.y;
        az += (float)v0.z + (float)v1.z + (float)v2.z + (float)v3.z;
        aw += (float)v0.w + (float)v1.w + (float)v2.w + (float)v3.w;
    }
    for (; e < dg; e++) {
        int s = cp[e];
        half4v v = P.xh[(size_t)s * 16 + c];
        ax += (float)v.x; ay += (float)v.y; az += (float)v.z; aw += (float)v.w;
    }
    size_t oidx = (size_t)row * 16 + c;
    if (P.fsub_h) {
        float d = P.rowscale[row];
        half4v f = P.fsub_h[oidx];
        ax = (float)f.x - ax * d; ay = (float)f.y - ay * d;
        az = (float)f.z - az * d; aw = (float)f.w - aw * d;
    } else {
        if (P.rowscale) { float d = P.rowscale[row]; ax *= d; ay *= d; az *= d; aw *= d; }
        if (P.bias) {
            float4 bb = ((const float4*)P.bias)[c];
            ax += bb.x; ay += bb.y; az += bb.z; aw += bb.w;
        }
        if (P.relu) {
            ax = fmaxf(ax, 0.f); ay = fmaxf(ay, 0.f);
            az = fmaxf(az, 0.f); aw = fmaxf(aw, 0.f);
        }
    }
    float mm = P.ms0 ? P.ms0[row] : 1.f;
    half4v h;
    h.x = (_Float16)(ax * mm); h.y = (_Float16)(ay * mm);
    h.z = (_Float16)(az * mm); h.w = (_Float16)(aw * mm);
    P.yh0[oidx] = h;
}

// F3: a3 (u-space, rows scaled by sqrt(deg)) -> out || a6 -> emb
__launch_bounds__(256)
__global__ void k_F3(const _Float16* __restrict__ u0h, const _Float16* __restrict__ u1h,
                     const _Float16* __restrict__ u2h, const half8* __restrict__ wcpk,
                     const float* __restrict__ b3, const float* __restrict__ dsq,
                     const float* __restrict__ W4, const float* __restrict__ b4,
                     float* __restrict__ outp,
                     const _Float16* __restrict__ sgh, const half8* __restrict__ Wg2pk,
                     const float* __restrict__ bg2, float* __restrict__ emb, int N) {
    int bx = blockIdx.x;
    if (bx < GB) {
        HSegs A;
        A.p[0] = u0h; A.ld[0] = 64;
        A.p[1] = u1h; A.ld[1] = 64;
        A.p[2] = u2h; A.ld[2] = 64;
        mg_dev<64, 192, true, true>(bx, A, wcpk, b3, 1, nullptr, nullptr, nullptr,
                                    dsq, W4, b4, outp, N);
        return;
    }
    bx -= GB;
    HSegs A;
    A.p[0] = sgh; A.ld[0] = 64;
    A.p[1] = nullptr; A.ld[1] = 0;
    A.p[2] = nullptr; A.ld[2] = 0;
    mg_dev<128, 64, false, false>(bx, A, Wg2pk, bg2, 0, emb, nullptr, nullptr,
                                  nullptr, nullptr, nullptr, nullptr, N);
}

extern "C" void kernel_launch(void* const* d_in, const int* in_sizes, int n_in,
                              void* d_out, int out_size, void* d_ws, size_t ws_size,
                              hipStream_t stream) {
    const int N = NN;
    const float* in_feat = (const float*)d_in[0];
    const int* src = (const int*)d_in[1];
    const int* dst = (const int*)d_in[2];
    const float* W1 = (const float*)d_in[3];
    const float* b1 = (const float*)d_in[4];
    const float* W2 = (const float*)d_in[5];
    const float* b2 = (const float*)d_in[6];
    const float* W3 = (const float*)d_in[7];
    const float* b3 = (const float*)d_in[8];
    const float* W4 = (const float*)d_in[9];
    const float* b4 = (const float*)d_in[10];
    const float* Wg1 = (const float*)d_in[11];
    const float* bg1 = (const float*)d_in[12];
    const float* Wg2 = (const float*)d_in[13];
    const float* bg2 = (const float*)d_in[14];

    float* out = (float*)d_out;                 // [N,2]
    float* emb = out + (size_t)N * 2;           // [N,128]

    // ---- workspace layout ----
    float* fw = (float*)d_ws;
    float* din  = fw;                      // [N]
    float* din2 = din + N;                 // [N]
    float* dsq  = din2 + N;                // [N]
    float* dout = dsq + N;                 // [N]
    int* degin  = (int*)(dout + N);        // [N]
    unsigned short* colsPad = (unsigned short*)(degin + N);   // [N*64] u16
    unsigned* HD   = (unsigned*)(colsPad + (size_t)64 * N);   // [64*25000]
    unsigned* HS   = HD + (size_t)C64 * NW;                   // [64*25000]
    unsigned* baseD = HS + (size_t)C64 * NW;                  // [64*25000]
    _Float16* hp = (_Float16*)(baseD + (size_t)C64 * NW);
    _Float16* h1h   = hp;                   // [N*64]
    _Float16* u0h   = h1h + (size_t)64 * N; // [N*64]  din*h
    _Float16* u1h   = u0h + (size_t)64 * N; // [N*64]  din*L1
    _Float16* u2h   = u1h + (size_t)64 * N; // [N*64]  din*L2
    _Float16* zh    = u2h + (size_t)64 * N; // [N*64]  Z (later *dout)
    _Float16* g1h   = zh + (size_t)64 * N;  // [N*64]  g1*dout
    _Float16* sgh   = g1h + (size_t)64 * N; // [N*64]  SG*din
    _Float16* W1pk  = sgh + (size_t)64 * N; // 8192
    _Float16* W2pk  = W1pk + 8192;          // 4096
    _Float16* Wg1pk = W2pk + 4096;          // 8192
    _Float16* Wg2pk = Wg1pk + 8192;         // 8192
    _Float16* wcpk  = Wg2pk + 8192;         // 12288

    // L0: weight packs
    k_init<<<160, 256, 0, stream>>>(W1, W1pk, W2, W2pk, Wg1, Wg1pk, Wg2, Wg2pk, W3, wcpk);

    // L1: LDS histograms || fused a1+a5
    k_L1<<<2 * HISTB + GB, 256, 0, stream>>>(src, dst, HD, HS, in_feat,
        (const half8*)W1pk, (const half8*)Wg1pk, b1, h1h, zh, N);

    // L2: degree reduce + norms || chunk prefix
    k_L2<<<2 * RB + RB, 256, 0, stream>>>(HD, HS, degin, din, din2, dsq, dout, baseD);

    // L3: atomic-free scatter || a2 (-> u0h) || zscale
    k_L3<<<HISTB + GB + ZSB, 256, 0, stream>>>(src, dst, baseD, colsPad,
        h1h, (const half8*)W2pk, b2, u0h, din, (half8*)zh, dout, N);

    // L4: FS1: u1 = u0 - (1/deg)*spmm(u0)  ||  g1h = dout*relu(din*spmm(zh)+bg1)
    SpmmP p0, p1;
    p0 = {(const half4v*)u0h, (const half4v*)u0h, din2, nullptr, (half4v*)u1h, nullptr, 0};
    p1 = {(const half4v*)zh, nullptr, din, bg1, (half4v*)g1h, dout, 1};
    k_FS<<<FSB, 256, 0, stream>>>(p0, p1, colsPad, degin, N);

    // L5: FS2: u2 = u1 - (1/deg)*spmm(u1)  ||  sgh = din*spmm(g1h)
    p0 = {(const half4v*)u1h, (const half4v*)u1h, din2, nullptr, (half4v*)u2h, nullptr, 0};
    p1 = {(const half4v*)g1h, nullptr, nullptr, nullptr, (half4v*)sgh, din, 0};
    k_FS<<<FSB, 256, 0, stream>>>(p0, p1, colsPad, degin, N);

    // L6: F3: out || emb
    k_F3<<<2 * GB, 256, 0, stream>>>(u0h, u1h, u2h, (const half8*)wcpk, b3, dsq,
        W4, b4, out, sgh, (const half8*)Wg2pk, bg2, emb, N);
}

// Round 12
// 259.151 us; speedup vs baseline: 1.6740x; 1.0272x over previous
//
#include <hip/hip_runtime.h>
#include <hip/hip_bf16.h>
#include <math.h>

#define NN 50000
#define NE 800000
#define C64 64        // edge chunks
#define CE 12500      // edges per chunk (NE/C64)
#define RW2 6250      // packed u32 words per node range (12500 nodes, 2/word)
#define NW 25000      // total packed words (NN/2)
#define HISTB 256     // hist/scatter blocks per direction (64 chunks x 4 ranges)
#define RB 98         // cdiv(NW,256)
#define GB 782        // cdiv(NN,64)
#define ZSB 782
#define FSG 3125      // FS groups: 16 rows per block
#define FSB 6250      // FS blocks: FSG x 2 (P0 | P1)

typedef _Float16 half8 __attribute__((ext_vector_type(8)));
typedef _Float16 half4v __attribute__((ext_vector_type(4)));
typedef float f32x4 __attribute__((ext_vector_type(4)));
typedef unsigned short ushort4v __attribute__((ext_vector_type(4)));

static inline int cdiv(int a, int b) { return (a + b - 1) / b; }

// ---------------- weight packing ----------------

// B-frag pack position for MFMA 16x16x32: W[k][n] (K x M, row-major)
__device__ inline size_t pack_pos(int k, int n, int K, int M) {
    int tile = n >> 4;
    int kstep = k >> 5;
    int quad = (k >> 3) & 3;
    int j = k & 7;
    int lane = (quad << 4) | (n & 15);
    return ((size_t)(tile * (K >> 5) + kstep) * 64 + lane) * 8 + j;
}

__device__ void pack_std_dev(int bx, const float* __restrict__ W, _Float16* __restrict__ Wpk,
                             int K, int M) {
    int idx = bx * 256 + threadIdx.x;
    if (idx >= K * M) return;
    int k = idx / M, n = idx % M;
    Wpk[pack_pos(k, n, K, M)] = (_Float16)W[idx];
}

__device__ void pack_wc_dev(int bx, const float* __restrict__ W3, _Float16* __restrict__ wcpk) {
    int idx = bx * 256 + threadIdx.x;
    if (idx >= 3 * 4096) return;
    int b = idx >> 12;
    int rem = idx & 4095;
    int k = rem >> 6, n = rem & 63;
    float w0 = W3[(0 * 64 + k) * 64 + n];
    float w1 = W3[(1 * 64 + k) * 64 + n];
    float w2 = W3[(2 * 64 + k) * 64 + n];
    float w3 = W3[(3 * 64 + k) * 64 + n];
    float w4 = W3[(4 * 64 + k) * 64 + n];
    float v;
    if (b == 0)      v = 3.f * w0;
    else if (b == 1) v = -3.f * w0 + 3.f * w1 + w3;
    else             v = 0.75f * w0 - 1.5f * w1 + 0.75f * w2 + w4;
    wcpk[pack_pos(b * 64 + k, n, 192, 64)] = (_Float16)v;
}

__launch_bounds__(256)
__global__ void k_init(const float* __restrict__ W1, _Float16* __restrict__ W1pk,
                       const float* __restrict__ W2, _Float16* __restrict__ W2pk,
                       const float* __restrict__ Wg1, _Float16* __restrict__ Wg1pk,
                       const float* __restrict__ Wg2, _Float16* __restrict__ Wg2pk,
                       const float* __restrict__ W3, _Float16* __restrict__ wcpk) {
    int bx = blockIdx.x;
    if (bx < 32) { pack_std_dev(bx, W1, W1pk, 128, 64); return; }
    bx -= 32;
    if (bx < 16) { pack_std_dev(bx, W2, W2pk, 64, 64); return; }
    bx -= 16;
    if (bx < 32) { pack_std_dev(bx, Wg1, Wg1pk, 128, 64); return; }
    bx -= 32;
    if (bx < 32) { pack_std_dev(bx, Wg2, Wg2pk, 64, 128); return; }
    bx -= 32;
    pack_wc_dev(bx, W3, wcpk);
}

// ---------------- atomic-free CSR build (4 node-ranges, 25 KB LDS) ----------------

// per-chunk, per-range LDS histogram (u16 pairs packed in u32)
__device__ void hist_dev(int bx, const int* __restrict__ idx, unsigned* __restrict__ H,
                         unsigned* __restrict__ cnt) {
    int c = bx & 63, r = bx >> 6;           // r in 0..3
    int tid = threadIdx.x;
    for (int j = tid; j < RW2; j += 256) cnt[j] = 0;
    __syncthreads();
    int lo = r * 12500;
    const int* p = idx + c * CE;
    for (int i = tid; i < CE; i += 256) {
        int v = p[i] - lo;
        if ((unsigned)v < 12500u)
            atomicAdd(&cnt[v >> 1], 1u << ((v & 1) * 16));
    }
    __syncthreads();
    unsigned* outp = H + (size_t)c * NW + r * RW2;
    for (int j = tid; j < RW2; j += 256) outp[j] = cnt[j];
}

__device__ void reduce_dev(int bx, const unsigned* __restrict__ H, int* __restrict__ dgo,
                           float* __restrict__ o_rsq, float* __restrict__ o_inv,
                           float* __restrict__ o_sq) {
    int w = bx * 256 + threadIdx.x;
    if (w >= NW) return;
    unsigned slo = 0, shi = 0;
#pragma unroll 8
    for (int c = 0; c < 64; c++) {
        unsigned h = H[(size_t)c * NW + w];
        slo += h & 0xffffu; shi += h >> 16;
    }
    if (dgo) {
        dgo[2 * w]     = slo > 64u ? 64 : (int)slo;
        dgo[2 * w + 1] = shi > 64u ? 64 : (int)shi;
    }
    float f0 = (float)(slo < 1u ? 1u : slo);
    float f1 = (float)(shi < 1u ? 1u : shi);
    o_rsq[2 * w] = rsqrtf(f0); o_rsq[2 * w + 1] = rsqrtf(f1);
    if (o_inv) { o_inv[2 * w] = 1.f / f0; o_inv[2 * w + 1] = 1.f / f1; }
    if (o_sq)  { o_sq[2 * w] = sqrtf(f0); o_sq[2 * w + 1] = sqrtf(f1); }
}

__device__ void prefix_dev(int bx, const unsigned* __restrict__ HD, unsigned* __restrict__ baseD) {
    int w = bx * 256 + threadIdx.x;
    if (w >= NW) return;
    unsigned slo = 0, shi = 0;
    for (int c = 0; c < 64; c++) {
        unsigned b0 = slo > 64u ? 64u : slo;
        unsigned b1 = shi > 64u ? 64u : shi;
        baseD[(size_t)c * NW + w] = b0 | (b1 << 16);
        unsigned h = HD[(size_t)c * NW + w];
        slo += h & 0xffffu; shi += h >> 16;
    }
}

// deterministic scatter: LDS counters INITIALIZED TO baseD slice, so the
// atomicAdd returns base+rank directly (no per-edge random L2 read).
__device__ void scatter_dev(int bx, const int* __restrict__ src, const int* __restrict__ dst,
                            const unsigned* __restrict__ baseD,
                            unsigned short* __restrict__ colsPad,
                            unsigned* __restrict__ cnt) {
    int c = bx & 63, r = bx >> 6;
    int tid = threadIdx.x;
    const unsigned* bslice = baseD + (size_t)c * NW + r * RW2;
    for (int j = tid; j < RW2; j += 256) cnt[j] = bslice[j];
    __syncthreads();
    int lo = r * 12500;
    const int* pd = dst + c * CE;
    const int* ps = src + c * CE;
    for (int i = tid; i < CE; i += 256) {
        int v = pd[i];
        int lv = v - lo;
        if ((unsigned)lv < 12500u) {
            int sh = (lv & 1) * 16;
            unsigned old = atomicAdd(&cnt[lv >> 1], 1u << sh);
            unsigned pos = (old >> sh) & 0xffffu;
            if (pos < 64u) colsPad[(size_t)v * 64 + pos] = (unsigned short)ps[i];
        }
    }
}

// zh *= dout (16 halves/thread)
__device__ void zscale_dev(int bx, half8* __restrict__ zh8, const float* __restrict__ dout, int N) {
    int idx = bx * 256 + threadIdx.x;
    if (idx >= N * 4) return;
    int row = idx >> 2;
    float m = dout[row];
    half8 a = zh8[idx * 2], b = zh8[idx * 2 + 1];
#pragma unroll
    for (int j = 0; j < 8; j++) {
        a[j] = (_Float16)((float)a[j] * m);
        b[j] = (_Float16)((float)b[j] * m);
    }
    zh8[idx * 2] = a; zh8[idx * 2 + 1] = b;
}

// ---------------- MFMA GEMM device functions (no LDS) ----------------

struct HSegs { const _Float16* p[3]; int ld[3]; };

template <int M, int K, bool OUTW, bool RSCA>
__device__ void mg_dev(int bx, HSegs A, const half8* __restrict__ Wpk,
                       const float* __restrict__ bias, int relu,
                       float* __restrict__ C,
                       _Float16* __restrict__ Ch0, const float* __restrict__ ms0,
                       const float* __restrict__ rsc,
                       const float* __restrict__ W4, const float* __restrict__ b4,
                       float* __restrict__ outp, int N) {
    constexpr int NT = M / 16;
    constexpr int NKS = K / 32;
    int tid = threadIdx.x;
    int wave = tid >> 6, lane = tid & 63;
    int quad = lane >> 4, m = lane & 15;
    int row0 = bx * 64 + wave * 16;
    int rowA = row0 + m; if (rowA >= N) rowA = N - 1;
    _Float16 hs = (_Float16)1.f;
    if (RSCA) hs = (_Float16)rsc[rowA];
    f32x4 acc[NT];
#pragma unroll
    for (int t = 0; t < NT; t++) acc[t] = (f32x4){0.f, 0.f, 0.f, 0.f};
#pragma unroll
    for (int ks = 0; ks < NKS; ks++) {
        const _Float16* ap = A.p[ks >> 1] + (size_t)rowA * A.ld[ks >> 1] + (ks & 1) * 32 + quad * 8;
        half8 af = *(const half8*)ap;
        if (RSCA) {
#pragma unroll
            for (int j = 0; j < 8; j++) af[j] *= hs;
        }
#pragma unroll
        for (int t = 0; t < NT; t++) {
            half8 bf = Wpk[(t * NKS + ks) * 64 + lane];
            acc[t] = __builtin_amdgcn_mfma_f32_16x16x32_f16(af, bf, acc[t], 0, 0, 0);
        }
    }
    float outv[NT][4];
#pragma unroll
    for (int t = 0; t < NT; t++) {
        float bv = bias ? bias[t * 16 + m] : 0.f;
#pragma unroll
        for (int r = 0; r < 4; r++) {
            float v = acc[t][r] + bv;
            if (relu) v = fmaxf(v, 0.f);
            outv[t][r] = v;
        }
    }
    if (OUTW) {
        float w40[NT], w41[NT];
#pragma unroll
        for (int t = 0; t < NT; t++) {
            w40[t] = W4[(t * 16 + m) * 2];
            w41[t] = W4[(t * 16 + m) * 2 + 1];
        }
#pragma unroll
        for (int r = 0; r < 4; r++) {
            float p0 = 0.f, p1 = 0.f;
#pragma unroll
            for (int t = 0; t < NT; t++) {
                p0 += outv[t][r] * w40[t];
                p1 += outv[t][r] * w41[t];
            }
#pragma unroll
            for (int off = 1; off < 16; off <<= 1) {
                p0 += __shfl_xor(p0, off);
                p1 += __shfl_xor(p1, off);
            }
            int row = row0 + quad * 4 + r;
            if (m == 0 && row < N) {
                outp[(size_t)row * 2 + 0] = p0 + b4[0];
                outp[(size_t)row * 2 + 1] = p1 + b4[1];
            }
        }
    }
    if (C || Ch0) {
#pragma unroll
        for (int r = 0; r < 4; r++) {
            int row = row0 + quad * 4 + r;
            if (row >= N) continue;
            float m0 = (Ch0 && ms0) ? ms0[row] : 1.f;
#pragma unroll
            for (int t = 0; t < NT; t++) {
                size_t off = (size_t)row * M + t * 16 + m;
                if (C)   C[off] = outv[t][r];
                if (Ch0) Ch0[off] = (_Float16)(outv[t][r] * m0);
            }
        }
    }
}

// fused a1+a5: shared A-fragments (f32 in_feat -> fp16), two B matrices
__device__ void a15_dev(int bx, const float* __restrict__ in_feat,
                        const half8* __restrict__ W1pk, const half8* __restrict__ Wg1pk,
                        const float* __restrict__ b1,
                        _Float16* __restrict__ h1h, _Float16* __restrict__ zh, int N) {
    int tid = threadIdx.x;
    int wave = tid >> 6, lane = tid & 63;
    int quad = lane >> 4, m = lane & 15;
    int row0 = bx * 64 + wave * 16;
    int rowA = row0 + m; if (rowA >= N) rowA = N - 1;
    f32x4 acc0[4], acc1[4];
#pragma unroll
    for (int t = 0; t < 4; t++) {
        acc0[t] = (f32x4){0.f, 0.f, 0.f, 0.f};
        acc1[t] = (f32x4){0.f, 0.f, 0.f, 0.f};
    }
#pragma unroll
    for (int ks = 0; ks < 4; ks++) {
        const float* ap = in_feat + (size_t)rowA * 128 + ks * 32 + quad * 8;
        float4 u = *(const float4*)ap;
        float4 v = *(const float4*)(ap + 4);
        half8 af;
        af[0] = (_Float16)u.x; af[1] = (_Float16)u.y; af[2] = (_Float16)u.z; af[3] = (_Float16)u.w;
        af[4] = (_Float16)v.x; af[5] = (_Float16)v.y; af[6] = (_Float16)v.z; af[7] = (_Float16)v.w;
#pragma unroll
        for (int t = 0; t < 4; t++) {
            acc0[t] = __builtin_amdgcn_mfma_f32_16x16x32_f16(af, W1pk[(t * 4 + ks) * 64 + lane], acc0[t], 0, 0, 0);
            acc1[t] = __builtin_amdgcn_mfma_f32_16x16x32_f16(af, Wg1pk[(t * 4 + ks) * 64 + lane], acc1[t], 0, 0, 0);
        }
    }
#pragma unroll
    for (int r = 0; r < 4; r++) {
        int row = row0 + quad * 4 + r;
        if (row >= N) continue;
#pragma unroll
        for (int t = 0; t < 4; t++) {
            float v0 = fmaxf(acc0[t][r] + b1[t * 16 + m], 0.f);
            h1h[(size_t)row * 64 + t * 16 + m] = (_Float16)v0;
            zh[(size_t)row * 64 + t * 16 + m] = (_Float16)acc1[t][r];
        }
    }
}

// ---------------- fused launch kernels ----------------

// L1: histD || histS || a15    (25 KB static LDS -> 6 blocks/CU)
__launch_bounds__(256)
__global__ void k_L1(const int* __restrict__ src, const int* __restrict__ dst,
                     unsigned* __restrict__ HD, unsigned* __restrict__ HS,
                     const float* __restrict__ in_feat,
                     const half8* __restrict__ W1pk, const half8* __restrict__ Wg1pk,
                     const float* __restrict__ b1,
                     _Float16* __restrict__ h1h, _Float16* __restrict__ zh, int N) {
    __shared__ unsigned cnt[RW2];
    int bx = blockIdx.x;
    if (bx < HISTB) { hist_dev(bx, dst, HD, cnt); return; }
    bx -= HISTB;
    if (bx < HISTB) { hist_dev(bx, src, HS, cnt); return; }
    bx -= HISTB;
    a15_dev(bx, in_feat, W1pk, Wg1pk, b1, h1h, zh, N);
}

// L2: reduce(dst) || reduce(src) || prefix
__launch_bounds__(256)
__global__ void k_L2(const unsigned* __restrict__ HD, const unsigned* __restrict__ HS,
                     int* __restrict__ degin, float* __restrict__ din,
                     float* __restrict__ din2, float* __restrict__ dsq,
                     float* __restrict__ dout, unsigned* __restrict__ baseD) {
    int bx = blockIdx.x;
    if (bx < RB) { reduce_dev(bx, HD, degin, din, din2, dsq); return; }
    bx -= RB;
    if (bx < RB) { reduce_dev(bx, HS, nullptr, dout, nullptr, nullptr); return; }
    bx -= RB;
    prefix_dev(bx, HD, baseD);
}

// L3: scatter || a2 (h1h@W2 -> u0h = din*relu(...)) || zscale
__launch_bounds__(256)
__global__ void k_L3(const int* __restrict__ src, const int* __restrict__ dst,
                     const unsigned* __restrict__ baseD, unsigned short* __restrict__ colsPad,
                     const _Float16* __restrict__ h1h, const half8* __restrict__ W2pk,
                     const float* __restrict__ b2, _Float16* __restrict__ u0h,
                     const float* __restrict__ din,
                     half8* __restrict__ zh8, const float* __restrict__ dout, int N) {
    __shared__ unsigned cnt[RW2];
    int bx = blockIdx.x;
    if (bx < HISTB) { scatter_dev(bx, src, dst, baseD, colsPad, cnt); return; }
    bx -= HISTB;
    if (bx < GB) {
        HSegs A;
        A.p[0] = h1h; A.ld[0] = 64;
        A.p[1] = nullptr; A.ld[1] = 0;
        A.p[2] = nullptr; A.ld[2] = 0;
        mg_dev<64, 64, false, false>(bx, A, W2pk, b2, 1, nullptr, u0h, din,
                                     nullptr, nullptr, nullptr, nullptr, N);
        return;
    }
    bx -= GB;
    zscale_dev(bx, zh8, dout, N);
}

// ---------------- pull SpMM: one quad per row, 8-deep gather unroll ----------------

struct SpmmP {
    const half4v* xh; const half4v* fsub_h; const float* rowscale; const float* bias;
    half4v* yh0; const float* ms0; int relu;
};

__launch_bounds__(256)
__global__ void k_FS(SpmmP P0, SpmmP P1, const unsigned short* __restrict__ colsPad,
                     const int* __restrict__ deg, int N) {
    int bx = blockIdx.x;
    bool first = bx < FSG;
    SpmmP P = first ? P0 : P1;
    int g = first ? bx : bx - FSG;
    int tid = threadIdx.x;
    int wave = tid >> 6, lane = tid & 63;
    int quad = lane >> 4, c = lane & 15;
    int row = g * 16 + wave * 4 + quad;
    if (row >= N) return;
    int dg = deg[row];
    const unsigned short* cp = colsPad + (size_t)row * 64;
    float ax = 0.f, ay = 0.f, az = 0.f, aw = 0.f;
    int e = 0;
    for (; e + 7 < dg; e += 8) {
        ushort4v sa = *(const ushort4v*)(cp + e);
        ushort4v sb = *(const ushort4v*)(cp + e + 4);
        half4v v0 = P.xh[(size_t)sa.x * 16 + c];
        half4v v1 = P.xh[(size_t)sa.y * 16 + c];
        half4v v2 = P.xh[(size_t)sa.z * 16 + c];
        half4v v3 = P.xh[(size_t)sa.w * 16 + c];
        half4v v4 = P.xh[(size_t)sb.x * 16 + c];
        half4v v5 = P.xh[(size_t)sb.y * 16 + c];
        half4v v6 = P.xh[(size_t)sb.z * 16 + c];
        half4v v7 = P.xh[(size_t)sb.w * 16 + c];
        ax += (float)v0.x + (float)v1.x + (float)v2.x + (float)v3.x
            + (float)v4.x + (float)v5.x + (float)v6.x + (float)v7.x;
        ay += (float)v0.y + (float)v1.y + (float)v2.y + (float)v3.y
            + (float)v4.y + (float)v5.y + (float)v6.y + (float)v7.y;
        az += (float)v0.z + (float)v1.z + (float)v2.z + (float)v3.z
            + (float)v4.z + (float)v5.z + (float)v6.z + (float)v7.z;
        aw += (float)v0.w + (float)v1.w + (float)v2.w + (float)v3.w
            + (float)v4.w + (float)v5.w + (float)v6.w + (float)v7.w;
    }
    for (; e + 3 < dg; e += 4) {
        ushort4v ss = *(const ushort4v*)(cp + e);
        half4v v0 = P.xh[(size_t)ss.x * 16 + c];
        half4v v1 = P.xh[(size_t)ss.y * 16 + c];
        half4v v2 = P.xh[(size_t)ss.z * 16 + c];
        half4v v3 = P.xh[(size_t)ss.w * 16 + c];
        ax += (float)v0.x + (float)v1.x + (float)v2.x + (float)v3.x;
        ay += (float)v0.y + (float)v1.y + (float)v2.y + (float)v3.y;
        az += (float)v0.z + (float)v1.z + (float)v2.z + (float)v3.z;
        aw += (float)v0.w + (float)v1.w + (float)v2.w + (float)v3.w;
    }
    for (; e < dg; e++) {
        int s = cp[e];
        half4v v = P.xh[(size_t)s * 16 + c];
        ax += (float)v.x; ay += (float)v.y; az += (float)v.z; aw += (float)v.w;
    }
    size_t oidx = (size_t)row * 16 + c;
    if (P.fsub_h) {
        float d = P.rowscale[row];
        half4v f = P.fsub_h[oidx];
        ax = (float)f.x - ax * d; ay = (float)f.y - ay * d;
        az = (float)f.z - az * d; aw = (float)f.w - aw * d;
    } else {
        if (P.rowscale) { float d = P.rowscale[row]; ax *= d; ay *= d; az *= d; aw *= d; }
        if (P.bias) {
            float4 bb = ((const float4*)P.bias)[c];
            ax += bb.x; ay += bb.y; az += bb.z; aw += bb.w;
        }
        if (P.relu) {
            ax = fmaxf(ax, 0.f); ay = fmaxf(ay, 0.f);
            az = fmaxf(az, 0.f); aw = fmaxf(aw, 0.f);
        }
    }
    float mm = P.ms0 ? P.ms0[row] : 1.f;
    half4v h;
    h.x = (_Float16)(ax * mm); h.y = (_Float16)(ay * mm);
    h.z = (_Float16)(az * mm); h.w = (_Float16)(aw * mm);
    P.yh0[oidx] = h;
}

// F3: a3 (u-space, rows scaled by sqrt(deg)) -> out || a6 -> emb
__launch_bounds__(256)
__global__ void k_F3(const _Float16* __restrict__ u0h, const _Float16* __restrict__ u1h,
                     const _Float16* __restrict__ u2h, const half8* __restrict__ wcpk,
                     const float* __restrict__ b3, const float* __restrict__ dsq,
                     const float* __restrict__ W4, const float* __restrict__ b4,
                     float* __restrict__ outp,
                     const _Float16* __restrict__ sgh, const half8* __restrict__ Wg2pk,
                     const float* __restrict__ bg2, float* __restrict__ emb, int N) {
    int bx = blockIdx.x;
    if (bx < GB) {
        HSegs A;
        A.p[0] = u0h; A.ld[0] = 64;
        A.p[1] = u1h; A.ld[1] = 64;
        A.p[2] = u2h; A.ld[2] = 64;
        mg_dev<64, 192, true, true>(bx, A, wcpk, b3, 1, nullptr, nullptr, nullptr,
                                    dsq, W4, b4, outp, N);
        return;
    }
    bx -= GB;
    HSegs A;
    A.p[0] = sgh; A.ld[0] = 64;
    A.p[1] = nullptr; A.ld[1] = 0;
    A.p[2] = nullptr; A.ld[2] = 0;
    mg_dev<128, 64, false, false>(bx, A, Wg2pk, bg2, 0, emb, nullptr, nullptr,
                                  nullptr, nullptr, nullptr, nullptr, N);
}

extern "C" void kernel_launch(void* const* d_in, const int* in_sizes, int n_in,
                              void* d_out, int out_size, void* d_ws, size_t ws_size,
                              hipStream_t stream) {
    const int N = NN;
    const float* in_feat = (const float*)d_in[0];
    const int* src = (const int*)d_in[1];
    const int* dst = (const int*)d_in[2];
    const float* W1 = (const float*)d_in[3];
    const float* b1 = (const float*)d_in[4];
    const float* W2 = (const float*)d_in[5];
    const float* b2 = (const float*)d_in[6];
    const float* W3 = (const float*)d_in[7];
    const float* b3 = (const float*)d_in[8];
    const float* W4 = (const float*)d_in[9];
    const float* b4 = (const float*)d_in[10];
    const float* Wg1 = (const float*)d_in[11];
    const float* bg1 = (const float*)d_in[12];
    const float* Wg2 = (const float*)d_in[13];
    const float* bg2 = (const float*)d_in[14];

    float* out = (float*)d_out;                 // [N,2]
    float* emb = out + (size_t)N * 2;           // [N,128]

    // ---- workspace layout ----
    float* fw = (float*)d_ws;
    float* din  = fw;                      // [N]
    float* din2 = din + N;                 // [N]
    float* dsq  = din2 + N;                // [N]
    float* dout = dsq + N;                 // [N]
    int* degin  = (int*)(dout + N);        // [N]
    unsigned short* colsPad = (unsigned short*)(degin + N);   // [N*64] u16
    unsigned* HD   = (unsigned*)(colsPad + (size_t)64 * N);   // [64*25000]
    unsigned* HS   = HD + (size_t)C64 * NW;                   // [64*25000]
    unsigned* baseD = HS + (size_t)C64 * NW;                  // [64*25000]
    _Float16* hp = (_Float16*)(baseD + (size_t)C64 * NW);
    _Float16* h1h   = hp;                   // [N*64]
    _Float16* u0h   = h1h + (size_t)64 * N; // [N*64]  din*h
    _Float16* u1h   = u0h + (size_t)64 * N; // [N*64]  din*L1
    _Float16* u2h   = u1h + (size_t)64 * N; // [N*64]  din*L2
    _Float16* zh    = u2h + (size_t)64 * N; // [N*64]  Z (later *dout)
    _Float16* g1h   = zh + (size_t)64 * N;  // [N*64]  g1*dout
    _Float16* sgh   = g1h + (size_t)64 * N; // [N*64]  SG*din
    _Float16* W1pk  = sgh + (size_t)64 * N; // 8192
    _Float16* W2pk  = W1pk + 8192;          // 4096
    _Float16* Wg1pk = W2pk + 4096;          // 8192
    _Float16* Wg2pk = Wg1pk + 8192;         // 8192
    _Float16* wcpk  = Wg2pk + 8192;         // 12288

    // L0: weight packs
    k_init<<<160, 256, 0, stream>>>(W1, W1pk, W2, W2pk, Wg1, Wg1pk, Wg2, Wg2pk, W3, wcpk);

    // L1: LDS histograms || fused a1+a5
    k_L1<<<2 * HISTB + GB, 256, 0, stream>>>(src, dst, HD, HS, in_feat,
        (const half8*)W1pk, (const half8*)Wg1pk, b1, h1h, zh, N);

    // L2: degree reduce + norms || chunk prefix
    k_L2<<<2 * RB + RB, 256, 0, stream>>>(HD, HS, degin, din, din2, dsq, dout, baseD);

    // L3: atomic-free scatter (base-seeded LDS counters) || a2 (-> u0h) || zscale
    k_L3<<<HISTB + GB + ZSB, 256, 0, stream>>>(src, dst, baseD, colsPad,
        h1h, (const half8*)W2pk, b2, u0h, din, (half8*)zh, dout, N);

    // L4: FS1: u1 = u0 - (1/deg)*spmm(u0)  ||  g1h = dout*relu(din*spmm(zh)+bg1)
    SpmmP p0, p1;
    p0 = {(const half4v*)u0h, (const half4v*)u0h, din2, nullptr, (half4v*)u1h, nullptr, 0};
    p1 = {(const half4v*)zh, nullptr, din, bg1, (half4v*)g1h, dout, 1};
    k_FS<<<FSB, 256, 0, stream>>>(p0, p1, colsPad, degin, N);

    // L5: FS2: u2 = u1 - (1/deg)*spmm(u1)  ||  sgh = din*spmm(g1h)
    p0 = {(const half4v*)u1h, (const half4v*)u1h, din2, nullptr, (half4v*)u2h, nullptr, 0};
    p1 = {(const half4v*)g1h, nullptr, nullptr, nullptr, (half4v*)sgh, din, 0};
    k_FS<<<FSB, 256, 0, stream>>>(p0, p1, colsPad, degin, N);

    // L6: F3: out || emb
    k_F3<<<2 * GB, 256, 0, stream>>>(u0h, u1h, u2h, (const half8*)wcpk, b3, dsq,
        W4, b4, out, sgh, (const half8*)Wg2pk, bg2, emb, N);
}